// Round 1
// baseline (824.730 us; speedup 1.0000x reference)
//
#include <hip/hip_runtime.h>
#include <cstdint>
#include <cstddef>

#define NN 50000
#define EE 800000
#define TOT_E (NN + EE)

static __device__ __forceinline__ float lrelu(float x) { return x > 0.f ? x : 0.2f * x; }

// ============================ CSR build ============================
__global__ void k_init_deg(int* __restrict__ cur) {
  int i = blockIdx.x * blockDim.x + threadIdx.x;
  if (i < NN) cur[i] = 1;  // self-loop
}
__global__ void k_count(const int* __restrict__ dst, int* __restrict__ cur) {
  int i = blockIdx.x * blockDim.x + threadIdx.x;
  if (i < EE) atomicAdd(&cur[dst[i]], 1);
}
__global__ __launch_bounds__(256) void k_scan1(const int* __restrict__ cur,
                                               int* __restrict__ rowp,
                                               int* __restrict__ blk) {
  __shared__ int sh[256];
  int tx = threadIdx.x;
  int i = blockIdx.x * 256 + tx;
  int v = (i < NN) ? cur[i] : 0;
  sh[tx] = v;
  __syncthreads();
  for (int off = 1; off < 256; off <<= 1) {
    int t = (tx >= off) ? sh[tx - off] : 0;
    __syncthreads();
    sh[tx] += t;
    __syncthreads();
  }
  if (i < NN) rowp[i] = sh[tx] - v;            // exclusive within block
  if (tx == 255) blk[blockIdx.x] = sh[255];    // block total
}
__global__ __launch_bounds__(256) void k_scan2(int* __restrict__ blk, int nb) {
  __shared__ int sh[256];
  int tx = threadIdx.x;
  int v = (tx < nb) ? blk[tx] : 0;
  sh[tx] = v;
  __syncthreads();
  for (int off = 1; off < 256; off <<= 1) {
    int t = (tx >= off) ? sh[tx - off] : 0;
    __syncthreads();
    sh[tx] += t;
    __syncthreads();
  }
  blk[tx] = sh[tx] - v;                        // exclusive
}
__global__ void k_scan3(int* __restrict__ rowp, int* __restrict__ cur,
                        const int* __restrict__ blk) {
  int i = blockIdx.x * 256 + threadIdx.x;
  if (i < NN) {
    int v = rowp[i] + blk[blockIdx.x];
    rowp[i] = v;
    cur[i] = v;
  }
  if (i == 0) rowp[NN] = TOT_E;
}
__global__ void k_fill_edges(const int* __restrict__ ei, int* __restrict__ cur,
                             int* __restrict__ srcl) {
  int i = blockIdx.x * blockDim.x + threadIdx.x;
  if (i < EE) {
    int s = ei[i];
    int d = ei[EE + i];
    int p = atomicAdd(&cur[d], 1);
    srcl[p] = s;
  }
}
__global__ void k_fill_loops(int* __restrict__ cur, int* __restrict__ srcl) {
  int i = blockIdx.x * blockDim.x + threadIdx.x;
  if (i < NN) {
    int p = atomicAdd(&cur[i], 1);
    srcl[p] = i;
  }
}

// ============================ BatchNorm ============================
template <int C>
__global__ __launch_bounds__(256) void k_bn_stats(const float* __restrict__ x,
                                                  float* __restrict__ sums) {
  constexpr int RP = 256 / C;
  int col = threadIdx.x % C;
  int rsub = threadIdx.x / C;
  float s = 0.f, q = 0.f;
  for (int r = blockIdx.x * RP + rsub; r < NN; r += gridDim.x * RP) {
    float v = x[(size_t)r * C + col];
    s += v;
    q += v * v;
  }
  __shared__ float bs[256], bq[256];
  bs[threadIdx.x] = s;
  bq[threadIdx.x] = q;
  __syncthreads();
  if (threadIdx.x < C) {
#pragma unroll
    for (int i = 1; i < RP; ++i) {
      s += bs[threadIdx.x + i * C];
      q += bq[threadIdx.x + i * C];
    }
    atomicAdd(&sums[col], s);
    atomicAdd(&sums[C + col], q);
  }
}
__global__ void k_bn_final(const float* __restrict__ sums, const float* __restrict__ g,
                           const float* __restrict__ b, float* __restrict__ ss, int C) {
  int c = threadIdx.x;
  if (c < C) {
    float invM = 1.f / (float)NN;
    float mu = sums[c] * invM;
    float var = sums[C + c] * invM - mu * mu;
    float sc = g[c] * rsqrtf(var + 1e-5f);
    ss[c] = sc;
    ss[128 + c] = b[c] - mu * sc;  // shift
  }
}
template <int C, bool RELU, bool SKIP>
__global__ void k_bn_apply(const float* __restrict__ x, const float* __restrict__ ss,
                           const float* __restrict__ skip, float* __restrict__ y) {
  const float4* x4 = (const float4*)x;
  const float4* ss4 = (const float4*)ss;
  const float4* sk4 = (const float4*)skip;
  float4* y4 = (float4*)y;
  int total = NN * C / 4;
  for (int i = blockIdx.x * blockDim.x + threadIdx.x; i < total;
       i += gridDim.x * blockDim.x) {
    int c4 = i % (C / 4);
    float4 v = x4[i];
    float4 a = ss4[c4];
    float4 sh = ss4[32 + c4];  // shift lives at float offset 128
    float4 o;
    o.x = v.x * a.x + sh.x;
    o.y = v.y * a.y + sh.y;
    o.z = v.z * a.z + sh.z;
    o.w = v.w * a.w + sh.w;
    if (SKIP) {
      float4 s = sk4[i];
      o.x += s.x; o.y += s.y; o.z += s.z; o.w += s.w;
    }
    if (RELU) {
      o.x = fmaxf(o.x, 0.f); o.y = fmaxf(o.y, 0.f);
      o.z = fmaxf(o.z, 0.f); o.w = fmaxf(o.w, 0.f);
    }
    y4[i] = o;
  }
}

// ============================ GEMM (fp32, Nout=128) ============================
// C[NN x 128] = A[NN x K] @ B[K x 128] (+bias) (+relu)
template <int K, bool BIAS, bool RELU>
__global__ __launch_bounds__(256) void k_gemm128(const float* __restrict__ A,
                                                 const float* __restrict__ B,
                                                 const float* __restrict__ bias,
                                                 float* __restrict__ C) {
  constexpr int BK = 16;
  __shared__ __align__(16) float As[BK][64];   // [k][row]
  __shared__ __align__(16) float4 Bs[BK][32];  // [k][col4]
  int tid = threadIdx.x;
  int r0 = blockIdx.x * 64;
  int tx = tid & 31;  // col4
  int ty = tid >> 5;  // row group (8 rows each)
  float acc[8][4];
#pragma unroll
  for (int i = 0; i < 8; ++i)
#pragma unroll
    for (int j = 0; j < 4; ++j) acc[i][j] = 0.f;

  int arow = tid >> 2;  // 0..63
  int aseg = tid & 3;   // k-float4 within BK
  int brow = tid >> 4;  // 0..15
  int bcol = tid & 15;  // float4 col (loads bcol and bcol+16)

  for (int kt = 0; kt < K; kt += BK) {
    float4 av = make_float4(0.f, 0.f, 0.f, 0.f);
    int gr = r0 + arow;
    if (gr < NN) av = *(const float4*)(A + (size_t)gr * K + kt + aseg * 4);
    As[aseg * 4 + 0][arow] = av.x;
    As[aseg * 4 + 1][arow] = av.y;
    As[aseg * 4 + 2][arow] = av.z;
    As[aseg * 4 + 3][arow] = av.w;
    Bs[brow][bcol]      = *(const float4*)(B + (size_t)(kt + brow) * 128 + bcol * 4);
    Bs[brow][bcol + 16] = *(const float4*)(B + (size_t)(kt + brow) * 128 + 64 + bcol * 4);
    __syncthreads();
#pragma unroll
    for (int kk = 0; kk < BK; ++kk) {
      float4 b = Bs[kk][tx];
      const float4* ar4 = (const float4*)&As[kk][ty * 8];
      float4 a0 = ar4[0];
      float4 a1 = ar4[1];
      float a[8] = {a0.x, a0.y, a0.z, a0.w, a1.x, a1.y, a1.z, a1.w};
#pragma unroll
      for (int i = 0; i < 8; ++i) {
        acc[i][0] = fmaf(a[i], b.x, acc[i][0]);
        acc[i][1] = fmaf(a[i], b.y, acc[i][1]);
        acc[i][2] = fmaf(a[i], b.z, acc[i][2]);
        acc[i][3] = fmaf(a[i], b.w, acc[i][3]);
      }
    }
    __syncthreads();
  }
  float4 bv = make_float4(0.f, 0.f, 0.f, 0.f);
  if (BIAS) bv = *(const float4*)(bias + tx * 4);
#pragma unroll
  for (int i = 0; i < 8; ++i) {
    int gr = r0 + ty * 8 + i;
    if (gr < NN) {
      float4 o;
      o.x = acc[i][0] + bv.x;
      o.y = acc[i][1] + bv.y;
      o.z = acc[i][2] + bv.z;
      o.w = acc[i][3] + bv.w;
      if (RELU) {
        o.x = fmaxf(o.x, 0.f); o.y = fmaxf(o.y, 0.f);
        o.z = fmaxf(o.z, 0.f); o.w = fmaxf(o.w, 0.f);
      }
      *(float4*)(C + (size_t)gr * 128 + tx * 4) = o;
    }
  }
}

// ============================ attention scores ============================
// sc_s[n,h] = sum_c hp[n,h*Cc+c]*a_s[h,c];  sc_d likewise. One wave per node.
template <int H>
__global__ __launch_bounds__(256) void k_sc(const float* __restrict__ hp,
                                            const float* __restrict__ a_s,
                                            const float* __restrict__ a_d,
                                            float* __restrict__ scs,
                                            float* __restrict__ scd) {
  int lane = threadIdx.x & 63;
  int n = (blockIdx.x * 256 + threadIdx.x) >> 6;
  if (n >= NN) return;
  const float2* hp2 = (const float2*)hp;
  const float2* as2 = (const float2*)a_s;
  const float2* ad2 = (const float2*)a_d;
  float2 v = hp2[(size_t)n * 64 + lane];
  float2 a = as2[lane];
  float2 d = ad2[lane];
  float ps = v.x * a.x + v.y * a.y;
  float pd = v.x * d.x + v.y * d.y;
  constexpr int LPH = 64 / H;  // lanes per head
#pragma unroll
  for (int off = 1; off < LPH; off <<= 1) {
    ps += __shfl_xor(ps, off);
    pd += __shfl_xor(pd, off);
  }
  if ((lane & (LPH - 1)) == 0) {
    int h = lane / LPH;
    scs[(size_t)n * H + h] = ps;
    scd[(size_t)n * H + h] = pd;
  }
}

// ============================ GAT aggregation ============================
// One wave per dst node. out[n,c] = bias[c] + sum_e alpha(e,head(c)) * hp[src_e, c]
template <int H>
__global__ __launch_bounds__(256) void k_agg(const float* __restrict__ hp,
                                             const float* __restrict__ scs,
                                             const float* __restrict__ scd,
                                             const int* __restrict__ rowp,
                                             const int* __restrict__ srcl,
                                             const float* __restrict__ bias,
                                             float* __restrict__ out) {
  int lane = threadIdx.x & 63;
  int n = (blockIdx.x * 256 + threadIdx.x) >> 6;
  if (n >= NN) return;
  int beg = rowp[n], end = rowp[n + 1];
  float sd[H], mx[H], sm[H];
#pragma unroll
  for (int h = 0; h < H; ++h) {
    sd[h] = scd[(size_t)n * H + h];
    mx[h] = -1e30f;
    sm[h] = 0.f;
  }
  // phase 1: per-head max over incoming edges
  for (int k = beg + lane; k < end; k += 64) {
    int s = srcl[k];
#pragma unroll
    for (int h = 0; h < H; ++h) {
      float e = lrelu(scs[(size_t)s * H + h] + sd[h]);
      mx[h] = fmaxf(mx[h], e);
    }
  }
#pragma unroll
  for (int off = 32; off; off >>= 1)
#pragma unroll
    for (int h = 0; h < H; ++h) mx[h] = fmaxf(mx[h], __shfl_xor(mx[h], off));
  // phase 2: sum of exp
  for (int k = beg + lane; k < end; k += 64) {
    int s = srcl[k];
#pragma unroll
    for (int h = 0; h < H; ++h) {
      float e = lrelu(scs[(size_t)s * H + h] + sd[h]);
      sm[h] += __expf(e - mx[h]);
    }
  }
#pragma unroll
  for (int off = 32; off; off >>= 1)
#pragma unroll
    for (int h = 0; h < H; ++h) sm[h] += __shfl_xor(sm[h], off);
  float inv[H];
#pragma unroll
  for (int h = 0; h < H; ++h) inv[h] = 1.f / (sm[h] + 1e-16f);
  // phase 3: weighted gather-accumulate; lane owns channels 2*lane, 2*lane+1
  int c0 = lane * 2;
  int hid = (H == 1) ? 0 : (c0 >> 5);
  float sdh = sd[hid], mh = mx[hid], ih = inv[hid];
  float a0 = 0.f, a1 = 0.f;
  const float2* hp2 = (const float2*)hp;
  for (int k = beg; k < end; ++k) {
    int s = srcl[k];
    float e = lrelu(scs[(size_t)s * H + hid] + sdh);
    float al = __expf(e - mh) * ih;
    float2 v = hp2[(size_t)s * 64 + lane];
    a0 = fmaf(al, v.x, a0);
    a1 = fmaf(al, v.y, a1);
  }
  const float2* b2 = (const float2*)bias;
  float2 bb = b2[lane];
  float2 o;
  o.x = a0 + bb.x;
  o.y = a1 + bb.y;
  *(float2*)(out + (size_t)n * 128 + c0) = o;
}

// ============================ fused classifier head ============================
__global__ __launch_bounds__(256) void k_classifier(
    const float* __restrict__ h, const float* __restrict__ W1, const float* __restrict__ b1,
    const float* __restrict__ W2, const float* __restrict__ b2, const float* __restrict__ W3,
    const float* __restrict__ b3, const float* __restrict__ cw, const float* __restrict__ cb,
    float* __restrict__ logits, float* __restrict__ conf) {
  __shared__ float W1s[128 * 64];
  __shared__ float W2s[64 * 32];
  __shared__ float sh[32 * 128];
  __shared__ float c1s[32 * 64];
  __shared__ float c2s[32 * 32];
  __shared__ float b1s[64], b2s[32], b3s[2], W3s[64], cws[128], cbs;
  int tid = threadIdx.x;
  for (int i = tid; i < 128 * 64; i += 256) W1s[i] = W1[i];
  for (int i = tid; i < 64 * 32; i += 256) W2s[i] = W2[i];
  if (tid < 64) { b1s[tid] = b1[tid]; W3s[tid] = W3[tid]; }
  if (tid < 32) b2s[tid] = b2[tid];
  if (tid < 2) b3s[tid] = b3[tid];
  if (tid < 128) cws[tid] = cw[tid];
  if (tid == 0) cbs = cb[0];
  int n0 = blockIdx.x * 32;
  for (int i = tid; i < 32 * 128; i += 256) {
    int r = n0 + i / 128;
    sh[i] = (r < NN) ? h[(size_t)r * 128 + (i % 128)] : 0.f;
  }
  __syncthreads();
  // c1 = relu(h @ W1 + b1): 32 nodes x 64 outs
  {
    int j = tid & 63;
    int nb = tid >> 6;
    for (int it = 0; it < 8; ++it) {
      int node = nb * 8 + it;
      float acc = b1s[j];
#pragma unroll 8
      for (int k = 0; k < 128; ++k) acc = fmaf(sh[node * 128 + k], W1s[k * 64 + j], acc);
      c1s[node * 64 + j] = fmaxf(acc, 0.f);
    }
  }
  __syncthreads();
  // c2 = relu(c1 @ W2 + b2): 32 nodes x 32 outs
  {
    int j = tid & 31;
    int nb = tid >> 5;
    for (int it = 0; it < 4; ++it) {
      int node = nb * 4 + it;
      float acc = b2s[j];
#pragma unroll 8
      for (int k = 0; k < 64; ++k) acc = fmaf(c1s[node * 64 + k], W2s[k * 32 + j], acc);
      c2s[node * 32 + j] = fmaxf(acc, 0.f);
    }
  }
  __syncthreads();
  if (tid < 64) {
    int node = tid >> 1, j = tid & 1;
    float acc = b3s[j];
#pragma unroll 8
    for (int k = 0; k < 32; ++k) acc = fmaf(c2s[node * 32 + k], W3s[k * 2 + j], acc);
    int n = n0 + node;
    if (n < NN) logits[(size_t)n * 2 + j] = acc;
  } else if (tid < 96) {
    int node = tid - 64;
    float acc = cbs;
#pragma unroll 8
    for (int k = 0; k < 128; ++k) acc = fmaf(sh[node * 128 + k], cws[k], acc);
    int n = n0 + node;
    if (n < NN) conf[n] = 1.f / (1.f + __expf(-acc));
  }
}

// ============================ launch ============================
extern "C" void kernel_launch(void* const* d_in, const int* in_sizes, int n_in,
                              void* d_out, int out_size, void* d_ws, size_t ws_size,
                              hipStream_t stream) {
  (void)in_sizes; (void)n_in; (void)out_size; (void)ws_size;
  const float* x       = (const float*)d_in[0];
  const int*   ei      = (const int*)d_in[1];
  const float* in_g    = (const float*)d_in[2];
  const float* in_b    = (const float*)d_in[3];
  const float* projW   = (const float*)d_in[4];
  const float* projb   = (const float*)d_in[5];
  const float* skipW   = (const float*)d_in[6];
  const float* skipb   = (const float*)d_in[7];
  const float* c1W     = (const float*)d_in[8];
  const float* c1as    = (const float*)d_in[9];
  const float* c1ad    = (const float*)d_in[10];
  const float* c1b     = (const float*)d_in[11];
  const float* bn1g    = (const float*)d_in[12];
  const float* bn1b    = (const float*)d_in[13];
  const float* c2W     = (const float*)d_in[14];
  const float* c2as    = (const float*)d_in[15];
  const float* c2ad    = (const float*)d_in[16];
  const float* c2b     = (const float*)d_in[17];
  const float* bn2g    = (const float*)d_in[18];
  const float* bn2b    = (const float*)d_in[19];
  const float* c3W     = (const float*)d_in[20];
  const float* c3as    = (const float*)d_in[21];
  const float* c3ad    = (const float*)d_in[22];
  const float* c3b     = (const float*)d_in[23];
  const float* bn3g    = (const float*)d_in[24];
  const float* bn3b    = (const float*)d_in[25];
  const float* clsW1   = (const float*)d_in[26];
  const float* clsb1   = (const float*)d_in[27];
  const float* clsW2   = (const float*)d_in[28];
  const float* clsb2   = (const float*)d_in[29];
  const float* clsW3   = (const float*)d_in[30];
  const float* clsb3   = (const float*)d_in[31];
  const float* confW   = (const float*)d_in[32];
  const float* confb   = (const float*)d_in[33];

  float* out_logits = (float*)d_out;
  float* out_conf   = (float*)d_out + (size_t)NN * 2;

  char* p = (char*)d_ws;
  auto alloc = [&](size_t bytes) -> char* {
    char* r = p;
    p += (bytes + 255) & ~(size_t)255;
    return r;
  };
  float* buf0  = (float*)alloc((size_t)NN * 128 * 4);
  float* buf1  = (float*)alloc((size_t)NN * 128 * 4);
  float* buf2  = (float*)alloc((size_t)NN * 128 * 4);
  float* buf3  = (float*)alloc((size_t)NN * 128 * 4);
  float* scs   = (float*)alloc((size_t)NN * 4 * 4);
  float* scd   = (float*)alloc((size_t)NN * 4 * 4);
  float* stats = (float*)alloc(256 * 4);
  float* ssb   = (float*)alloc(256 * 4);
  int*   rowp  = (int*)alloc((size_t)(NN + 1) * 4);
  int*   cur   = (int*)alloc((size_t)NN * 4);
  int*   blk   = (int*)alloc(256 * 4);
  int*   srcl  = (int*)alloc((size_t)TOT_E * 4);

  const int NB_N = (NN + 255) / 256;     // 196
  const int NB_E = (EE + 255) / 256;     // 3125
  const int GB   = (NN + 63) / 64;       // 782
  const int WB   = (NN + 3) / 4;         // 12500 (wave-per-node kernels)
  const int CB   = (NN + 31) / 32;       // 1563

  // ---- CSR build ----
  k_init_deg<<<NB_N, 256, 0, stream>>>(cur);
  k_count<<<NB_E, 256, 0, stream>>>(ei + EE, cur);
  k_scan1<<<NB_N, 256, 0, stream>>>(cur, rowp, blk);
  k_scan2<<<1, 256, 0, stream>>>(blk, NB_N);
  k_scan3<<<NB_N, 256, 0, stream>>>(rowp, cur, blk);
  k_fill_edges<<<NB_E, 256, 0, stream>>>(ei, cur, srcl);
  k_fill_loops<<<NB_N, 256, 0, stream>>>(cur, srcl);

  // ---- input BN -> xb (buf2) ----
  hipMemsetAsync(stats, 0, 1024, stream);
  k_bn_stats<64><<<256, 256, 0, stream>>>(x, stats);
  k_bn_final<<<1, 128, 0, stream>>>(stats, in_g, in_b, ssb, 64);
  k_bn_apply<64, false, false><<<1024, 256, 0, stream>>>(x, ssb, nullptr, buf2);

  // ---- proj (+relu) -> hr (buf0); skip -> buf1 ----
  k_gemm128<64, true, true><<<GB, 256, 0, stream>>>(buf2, projW, projb, buf0);
  k_gemm128<128, true, false><<<GB, 256, 0, stream>>>(buf0, skipW, skipb, buf1);

  // ---- GAT layer 1 (input buf0) ----
  k_gemm128<128, false, false><<<GB, 256, 0, stream>>>(buf0, c1W, nullptr, buf2);
  k_sc<4><<<WB, 256, 0, stream>>>(buf2, c1as, c1ad, scs, scd);
  k_agg<4><<<WB, 256, 0, stream>>>(buf2, scs, scd, rowp, srcl, c1b, buf3);
  hipMemsetAsync(stats, 0, 1024, stream);
  k_bn_stats<128><<<256, 256, 0, stream>>>(buf3, stats);
  k_bn_final<<<1, 128, 0, stream>>>(stats, bn1g, bn1b, ssb, 128);
  k_bn_apply<128, true, false><<<2048, 256, 0, stream>>>(buf3, ssb, nullptr, buf3);

  // ---- GAT layer 2 (input buf3) ----
  k_gemm128<128, false, false><<<GB, 256, 0, stream>>>(buf3, c2W, nullptr, buf2);
  k_sc<4><<<WB, 256, 0, stream>>>(buf2, c2as, c2ad, scs, scd);
  k_agg<4><<<WB, 256, 0, stream>>>(buf2, scs, scd, rowp, srcl, c2b, buf0);
  hipMemsetAsync(stats, 0, 1024, stream);
  k_bn_stats<128><<<256, 256, 0, stream>>>(buf0, stats);
  k_bn_final<<<1, 128, 0, stream>>>(stats, bn2g, bn2b, ssb, 128);
  k_bn_apply<128, true, false><<<2048, 256, 0, stream>>>(buf0, ssb, nullptr, buf0);

  // ---- GAT layer 3 (input buf0, H=1) ----
  k_gemm128<128, false, false><<<GB, 256, 0, stream>>>(buf0, c3W, nullptr, buf2);
  k_sc<1><<<WB, 256, 0, stream>>>(buf2, c3as, c3ad, scs, scd);
  k_agg<1><<<WB, 256, 0, stream>>>(buf2, scs, scd, rowp, srcl, c3b, buf3);
  hipMemsetAsync(stats, 0, 1024, stream);
  k_bn_stats<128><<<256, 256, 0, stream>>>(buf3, stats);
  k_bn_final<<<1, 128, 0, stream>>>(stats, bn3g, bn3b, ssb, 128);
  k_bn_apply<128, true, true><<<2048, 256, 0, stream>>>(buf3, ssb, buf1, buf3);

  // ---- classifier head ----
  k_classifier<<<CB, 256, 0, stream>>>(buf3, clsW1, clsb1, clsW2, clsb2, clsW3, clsb3,
                                       confW, confb, out_logits, out_conf);
}

// Round 2
// 644.359 us; speedup vs baseline: 1.2799x; 1.2799x over previous
//
#include <hip/hip_runtime.h>
#include <cstdint>
#include <cstddef>

#define NN 50000
#define EE 800000
#define TOT_E (NN + EE)

static __device__ __forceinline__ float lrelu(float x) { return x > 0.f ? x : 0.2f * x; }

static __device__ __forceinline__ unsigned short f2bf(float f) {
  union { float f; unsigned u; } v;
  v.f = f;
  unsigned r = v.u + 0x7FFFu + ((v.u >> 16) & 1u);  // round-to-nearest-even
  return (unsigned short)(r >> 16);
}
static __device__ __forceinline__ float bf2f_lo(unsigned u) {
  union { unsigned u; float f; } v;
  v.u = u << 16;
  return v.f;
}
static __device__ __forceinline__ float bf2f_hi(unsigned u) {
  union { unsigned u; float f; } v;
  v.u = u & 0xFFFF0000u;
  return v.f;
}

// ============================ CSR build ============================
__global__ void k_init_deg(int* __restrict__ cur) {
  int i = blockIdx.x * blockDim.x + threadIdx.x;
  if (i < NN) cur[i] = 1;  // self-loop
}
__global__ void k_count(const int* __restrict__ dst, int* __restrict__ cur) {
  int i = blockIdx.x * blockDim.x + threadIdx.x;
  if (i < EE) atomicAdd(&cur[dst[i]], 1);
}
__global__ __launch_bounds__(256) void k_scan1(const int* __restrict__ cur,
                                               int* __restrict__ rowp,
                                               int* __restrict__ blk) {
  __shared__ int sh[256];
  int tx = threadIdx.x;
  int i = blockIdx.x * 256 + tx;
  int v = (i < NN) ? cur[i] : 0;
  sh[tx] = v;
  __syncthreads();
  for (int off = 1; off < 256; off <<= 1) {
    int t = (tx >= off) ? sh[tx - off] : 0;
    __syncthreads();
    sh[tx] += t;
    __syncthreads();
  }
  if (i < NN) rowp[i] = sh[tx] - v;
  if (tx == 255) blk[blockIdx.x] = sh[255];
}
__global__ __launch_bounds__(256) void k_scan2(int* __restrict__ blk, int nb) {
  __shared__ int sh[256];
  int tx = threadIdx.x;
  int v = (tx < nb) ? blk[tx] : 0;
  sh[tx] = v;
  __syncthreads();
  for (int off = 1; off < 256; off <<= 1) {
    int t = (tx >= off) ? sh[tx - off] : 0;
    __syncthreads();
    sh[tx] += t;
    __syncthreads();
  }
  blk[tx] = sh[tx] - v;
}
__global__ void k_scan3(int* __restrict__ rowp, int* __restrict__ cur,
                        const int* __restrict__ blk) {
  int i = blockIdx.x * 256 + threadIdx.x;
  if (i < NN) {
    int v = rowp[i] + blk[blockIdx.x];
    rowp[i] = v;
    cur[i] = v;
  }
  if (i == 0) rowp[NN] = TOT_E;
}
__global__ void k_fill_edges(const int* __restrict__ ei, int* __restrict__ cur,
                             int* __restrict__ srcl) {
  int i = blockIdx.x * blockDim.x + threadIdx.x;
  if (i < EE) {
    int s = ei[i];
    int d = ei[EE + i];
    int p = atomicAdd(&cur[d], 1);
    srcl[p] = s;
  }
}
__global__ void k_fill_loops(int* __restrict__ cur, int* __restrict__ srcl) {
  int i = blockIdx.x * blockDim.x + threadIdx.x;
  if (i < NN) {
    int p = atomicAdd(&cur[i], 1);
    srcl[p] = i;
  }
}

// ============================ BatchNorm stats ============================
template <int C>
__global__ __launch_bounds__(256) void k_bn_stats(const float* __restrict__ x,
                                                  float* __restrict__ sums) {
  constexpr int RP = 256 / C;
  int col = threadIdx.x % C;
  int rsub = threadIdx.x / C;
  float s = 0.f, q = 0.f;
  for (int r = blockIdx.x * RP + rsub; r < NN; r += gridDim.x * RP) {
    float v = x[(size_t)r * C + col];
    s += v;
    q += v * v;
  }
  __shared__ float bs[256], bq[256];
  bs[threadIdx.x] = s;
  bq[threadIdx.x] = q;
  __syncthreads();
  if (threadIdx.x < C) {
#pragma unroll
    for (int i = 1; i < RP; ++i) {
      s += bs[threadIdx.x + i * C];
      q += bq[threadIdx.x + i * C];
    }
    atomicAdd(&sums[col], s);
    atomicAdd(&sums[C + col], q);
  }
}
__global__ void k_bn_final(const float* __restrict__ sums, const float* __restrict__ g,
                           const float* __restrict__ b, float* __restrict__ ss, int C) {
  int c = threadIdx.x;
  if (c < C) {
    float invM = 1.f / (float)NN;
    float mu = sums[c] * invM;
    float var = sums[C + c] * invM - mu * mu;
    float sc = g[c] * rsqrtf(var + 1e-5f);
    ss[c] = sc;
    ss[128 + c] = b[c] - mu * sc;  // shift
  }
}
// standalone apply (only for bn3: + skip + relu)
template <int C, bool RELU, bool SKIP>
__global__ void k_bn_apply(const float* __restrict__ x, const float* __restrict__ ss,
                           const float* __restrict__ skip, float* __restrict__ y) {
  const float4* x4 = (const float4*)x;
  const float4* ss4 = (const float4*)ss;
  const float4* sk4 = (const float4*)skip;
  float4* y4 = (float4*)y;
  int total = NN * C / 4;
  for (int i = blockIdx.x * blockDim.x + threadIdx.x; i < total;
       i += gridDim.x * blockDim.x) {
    int c4 = i % (C / 4);
    float4 v = x4[i];
    float4 a = ss4[c4];
    float4 sh = ss4[32 + c4];
    float4 o;
    o.x = v.x * a.x + sh.x;
    o.y = v.y * a.y + sh.y;
    o.z = v.z * a.z + sh.z;
    o.w = v.w * a.w + sh.w;
    if (SKIP) {
      float4 s = sk4[i];
      o.x += s.x; o.y += s.y; o.z += s.z; o.w += s.w;
    }
    if (RELU) {
      o.x = fmaxf(o.x, 0.f); o.y = fmaxf(o.y, 0.f);
      o.z = fmaxf(o.z, 0.f); o.w = fmaxf(o.w, 0.f);
    }
    y4[i] = o;
  }
}

// ============================ GEMM (fp32, Nout=128) ============================
// C[NN x 128] = op_bn(A)[NN x K] @ B[K x 128] (+bias) (+relu), optional bf16 out.
// BN: 0 = none, 1 = scale/shift, 2 = scale/shift + relu (applied to A elements)
template <int K, bool BIAS, bool RELU, int BN, bool OUTBF>
__global__ __launch_bounds__(256) void k_gemm128(const float* __restrict__ A,
                                                 const float* __restrict__ B,
                                                 const float* __restrict__ bias,
                                                 void* __restrict__ Cout,
                                                 const float* __restrict__ bnss) {
  constexpr int BK = 16;
  __shared__ __align__(16) float As[BK][64];   // [k][row]
  __shared__ __align__(16) float4 Bs[BK][32];  // [k][col4]
  int tid = threadIdx.x;
  int r0 = blockIdx.x * 64;
  int tx = tid & 31;  // col4
  int ty = tid >> 5;  // row group (8 rows each)
  float acc[8][4];
#pragma unroll
  for (int i = 0; i < 8; ++i)
#pragma unroll
    for (int j = 0; j < 4; ++j) acc[i][j] = 0.f;

  int arow = tid >> 2;  // 0..63
  int aseg = tid & 3;   // k-float4 within BK
  int brow = tid >> 4;  // 0..15
  int bcol = tid & 15;  // float4 col

  for (int kt = 0; kt < K; kt += BK) {
    float4 av = make_float4(0.f, 0.f, 0.f, 0.f);
    int gr = r0 + arow;
    if (gr < NN) av = *(const float4*)(A + (size_t)gr * K + kt + aseg * 4);
    if (BN) {
      float4 sc = *(const float4*)(bnss + kt + aseg * 4);
      float4 sh = *(const float4*)(bnss + 128 + kt + aseg * 4);
      av.x = av.x * sc.x + sh.x;
      av.y = av.y * sc.y + sh.y;
      av.z = av.z * sc.z + sh.z;
      av.w = av.w * sc.w + sh.w;
      if (BN == 2) {
        av.x = fmaxf(av.x, 0.f); av.y = fmaxf(av.y, 0.f);
        av.z = fmaxf(av.z, 0.f); av.w = fmaxf(av.w, 0.f);
      }
    }
    As[aseg * 4 + 0][arow] = av.x;
    As[aseg * 4 + 1][arow] = av.y;
    As[aseg * 4 + 2][arow] = av.z;
    As[aseg * 4 + 3][arow] = av.w;
    Bs[brow][bcol]      = *(const float4*)(B + (size_t)(kt + brow) * 128 + bcol * 4);
    Bs[brow][bcol + 16] = *(const float4*)(B + (size_t)(kt + brow) * 128 + 64 + bcol * 4);
    __syncthreads();
#pragma unroll
    for (int kk = 0; kk < BK; ++kk) {
      float4 b = Bs[kk][tx];
      const float4* ar4 = (const float4*)&As[kk][ty * 8];
      float4 a0 = ar4[0];
      float4 a1 = ar4[1];
      float a[8] = {a0.x, a0.y, a0.z, a0.w, a1.x, a1.y, a1.z, a1.w};
#pragma unroll
      for (int i = 0; i < 8; ++i) {
        acc[i][0] = fmaf(a[i], b.x, acc[i][0]);
        acc[i][1] = fmaf(a[i], b.y, acc[i][1]);
        acc[i][2] = fmaf(a[i], b.z, acc[i][2]);
        acc[i][3] = fmaf(a[i], b.w, acc[i][3]);
      }
    }
    __syncthreads();
  }
  float4 bv = make_float4(0.f, 0.f, 0.f, 0.f);
  if (BIAS) bv = *(const float4*)(bias + tx * 4);
#pragma unroll
  for (int i = 0; i < 8; ++i) {
    int gr = r0 + ty * 8 + i;
    if (gr < NN) {
      float4 o;
      o.x = acc[i][0] + bv.x;
      o.y = acc[i][1] + bv.y;
      o.z = acc[i][2] + bv.z;
      o.w = acc[i][3] + bv.w;
      if (RELU) {
        o.x = fmaxf(o.x, 0.f); o.y = fmaxf(o.y, 0.f);
        o.z = fmaxf(o.z, 0.f); o.w = fmaxf(o.w, 0.f);
      }
      if (OUTBF) {
        ushort4 ov;
        ov.x = f2bf(o.x); ov.y = f2bf(o.y); ov.z = f2bf(o.z); ov.w = f2bf(o.w);
        *(ushort4*)((unsigned short*)Cout + (size_t)gr * 128 + tx * 4) = ov;
      } else {
        *(float4*)((float*)Cout + (size_t)gr * 128 + tx * 4) = o;
      }
    }
  }
}

// ============================ attention scores (bf16 h) ============================
template <int H>
__global__ __launch_bounds__(256) void k_sc(const unsigned short* __restrict__ hp,
                                            const float* __restrict__ a_s,
                                            const float* __restrict__ a_d,
                                            float* __restrict__ scs,
                                            float* __restrict__ scd) {
  int lane = threadIdx.x & 63;
  int n = (blockIdx.x * 256 + threadIdx.x) >> 6;
  if (n >= NN) return;
  unsigned u = *(const unsigned*)(hp + (size_t)n * 128 + lane * 2);
  float vx = bf2f_lo(u), vy = bf2f_hi(u);
  const float2* as2 = (const float2*)a_s;
  const float2* ad2 = (const float2*)a_d;
  float2 a = as2[lane];
  float2 d = ad2[lane];
  float ps = vx * a.x + vy * a.y;
  float pd = vx * d.x + vy * d.y;
  constexpr int LPH = 64 / H;
#pragma unroll
  for (int off = 1; off < LPH; off <<= 1) {
    ps += __shfl_xor(ps, off);
    pd += __shfl_xor(pd, off);
  }
  if ((lane & (LPH - 1)) == 0) {
    int h = lane / LPH;
    scs[(size_t)n * H + h] = ps;
    scd[(size_t)n * H + h] = pd;
  }
}

// ============================ GAT aggregation (single pass) ============================
// softmax(e - m) == softmax(e): skip the max pass. One wave per dst node; half-wave 0
// handles even edge slots, half-wave 1 odd slots; lane owns 4 channels (bf16 gather).
template <int H>
__global__ __launch_bounds__(256) void k_agg(const unsigned short* __restrict__ hp,
                                             const float* __restrict__ scs,
                                             const float* __restrict__ scd,
                                             const int* __restrict__ rowp,
                                             const int* __restrict__ srcl,
                                             const float* __restrict__ bias,
                                             float* __restrict__ out) {
  int lane = threadIdx.x & 63;
  int n = (blockIdx.x * 256 + threadIdx.x) >> 6;
  if (n >= NN) return;
  int half = lane >> 5;
  int l32 = lane & 31;
  int c0 = l32 * 4;
  int hid = (H == 1) ? 0 : (l32 >> 3);
  float sd = scd[(size_t)n * H + hid];
  int beg = rowp[n], end = rowp[n + 1];
  float a0 = 0.f, a1 = 0.f, a2 = 0.f, a3 = 0.f, sw = 0.f;
  for (int k = beg + half; k < end; k += 2) {
    int s = srcl[k];
    float e = lrelu(scs[(size_t)s * H + hid] + sd);
    float w = __expf(e);
    uint2 u = *(const uint2*)(hp + (size_t)s * 128 + c0);
    a0 = fmaf(w, bf2f_lo(u.x), a0);
    a1 = fmaf(w, bf2f_hi(u.x), a1);
    a2 = fmaf(w, bf2f_lo(u.y), a2);
    a3 = fmaf(w, bf2f_hi(u.y), a3);
    sw += w;
  }
  a0 += __shfl_xor(a0, 32);
  a1 += __shfl_xor(a1, 32);
  a2 += __shfl_xor(a2, 32);
  a3 += __shfl_xor(a3, 32);
  sw += __shfl_xor(sw, 32);
  if (half == 0) {
    float inv = 1.f / (sw + 1e-16f);
    float4 bb = *(const float4*)(bias + c0);
    float4 o;
    o.x = a0 * inv + bb.x;
    o.y = a1 * inv + bb.y;
    o.z = a2 * inv + bb.z;
    o.w = a3 * inv + bb.w;
    *(float4*)(out + (size_t)n * 128 + c0) = o;
  }
}

// ============================ fused classifier head ============================
__global__ __launch_bounds__(256) void k_classifier(
    const float* __restrict__ h, const float* __restrict__ W1, const float* __restrict__ b1,
    const float* __restrict__ W2, const float* __restrict__ b2, const float* __restrict__ W3,
    const float* __restrict__ b3, const float* __restrict__ cw, const float* __restrict__ cb,
    float* __restrict__ logits, float* __restrict__ conf) {
  __shared__ float W1s[128 * 64];
  __shared__ float W2s[64 * 32];
  __shared__ float sh[32 * 128];
  __shared__ float c1s[32 * 64];
  __shared__ float c2s[32 * 32];
  __shared__ float b1s[64], b2s[32], b3s[2], W3s[64], cws[128], cbs;
  int tid = threadIdx.x;
  for (int i = tid; i < 128 * 64; i += 256) W1s[i] = W1[i];
  for (int i = tid; i < 64 * 32; i += 256) W2s[i] = W2[i];
  if (tid < 64) { b1s[tid] = b1[tid]; W3s[tid] = W3[tid]; }
  if (tid < 32) b2s[tid] = b2[tid];
  if (tid < 2) b3s[tid] = b3[tid];
  if (tid < 128) cws[tid] = cw[tid];
  if (tid == 0) cbs = cb[0];
  int n0 = blockIdx.x * 32;
  for (int i = tid; i < 32 * 128; i += 256) {
    int r = n0 + i / 128;
    sh[i] = (r < NN) ? h[(size_t)r * 128 + (i % 128)] : 0.f;
  }
  __syncthreads();
  {
    int j = tid & 63;
    int nb = tid >> 6;
    for (int it = 0; it < 8; ++it) {
      int node = nb * 8 + it;
      float acc = b1s[j];
#pragma unroll 8
      for (int k = 0; k < 128; ++k) acc = fmaf(sh[node * 128 + k], W1s[k * 64 + j], acc);
      c1s[node * 64 + j] = fmaxf(acc, 0.f);
    }
  }
  __syncthreads();
  {
    int j = tid & 31;
    int nb = tid >> 5;
    for (int it = 0; it < 4; ++it) {
      int node = nb * 4 + it;
      float acc = b2s[j];
#pragma unroll 8
      for (int k = 0; k < 64; ++k) acc = fmaf(c1s[node * 64 + k], W2s[k * 32 + j], acc);
      c2s[node * 32 + j] = fmaxf(acc, 0.f);
    }
  }
  __syncthreads();
  if (tid < 64) {
    int node = tid >> 1, j = tid & 1;
    float acc = b3s[j];
#pragma unroll 8
    for (int k = 0; k < 32; ++k) acc = fmaf(c2s[node * 32 + k], W3s[k * 2 + j], acc);
    int n = n0 + node;
    if (n < NN) logits[(size_t)n * 2 + j] = acc;
  } else if (tid < 96) {
    int node = tid - 64;
    float acc = cbs;
#pragma unroll 8
    for (int k = 0; k < 128; ++k) acc = fmaf(sh[node * 128 + k], cws[k], acc);
    int n = n0 + node;
    if (n < NN) conf[n] = 1.f / (1.f + __expf(-acc));
  }
}

// ============================ launch ============================
extern "C" void kernel_launch(void* const* d_in, const int* in_sizes, int n_in,
                              void* d_out, int out_size, void* d_ws, size_t ws_size,
                              hipStream_t stream) {
  (void)in_sizes; (void)n_in; (void)out_size; (void)ws_size;
  const float* x       = (const float*)d_in[0];
  const int*   ei      = (const int*)d_in[1];
  const float* in_g    = (const float*)d_in[2];
  const float* in_b    = (const float*)d_in[3];
  const float* projW   = (const float*)d_in[4];
  const float* projb   = (const float*)d_in[5];
  const float* skipW   = (const float*)d_in[6];
  const float* skipb   = (const float*)d_in[7];
  const float* c1W     = (const float*)d_in[8];
  const float* c1as    = (const float*)d_in[9];
  const float* c1ad    = (const float*)d_in[10];
  const float* c1b     = (const float*)d_in[11];
  const float* bn1g    = (const float*)d_in[12];
  const float* bn1b    = (const float*)d_in[13];
  const float* c2W     = (const float*)d_in[14];
  const float* c2as    = (const float*)d_in[15];
  const float* c2ad    = (const float*)d_in[16];
  const float* c2b     = (const float*)d_in[17];
  const float* bn2g    = (const float*)d_in[18];
  const float* bn2b    = (const float*)d_in[19];
  const float* c3W     = (const float*)d_in[20];
  const float* c3as    = (const float*)d_in[21];
  const float* c3ad    = (const float*)d_in[22];
  const float* c3b     = (const float*)d_in[23];
  const float* bn3g    = (const float*)d_in[24];
  const float* bn3b    = (const float*)d_in[25];
  const float* clsW1   = (const float*)d_in[26];
  const float* clsb1   = (const float*)d_in[27];
  const float* clsW2   = (const float*)d_in[28];
  const float* clsb2   = (const float*)d_in[29];
  const float* clsW3   = (const float*)d_in[30];
  const float* clsb3   = (const float*)d_in[31];
  const float* confW   = (const float*)d_in[32];
  const float* confb   = (const float*)d_in[33];

  float* out_logits = (float*)d_out;
  float* out_conf   = (float*)d_out + (size_t)NN * 2;

  char* p = (char*)d_ws;
  auto alloc = [&](size_t bytes) -> char* {
    char* r = p;
    p += (bytes + 255) & ~(size_t)255;
    return r;
  };
  float* buf0  = (float*)alloc((size_t)NN * 128 * 4);   // hr / agg2 out
  float* buf1  = (float*)alloc((size_t)NN * 128 * 4);   // h_skip
  float* buf3  = (float*)alloc((size_t)NN * 128 * 4);   // agg1/agg3 out, final h
  unsigned short* hb = (unsigned short*)alloc((size_t)NN * 128 * 2);  // bf16 conv out
  float* scs   = (float*)alloc((size_t)NN * 4 * 4);
  float* scd   = (float*)alloc((size_t)NN * 4 * 4);
  float* stats = (float*)alloc(256 * 4);
  float* ssb   = (float*)alloc(256 * 4);
  int*   rowp  = (int*)alloc((size_t)(NN + 1) * 4);
  int*   cur   = (int*)alloc((size_t)NN * 4);
  int*   blk   = (int*)alloc(256 * 4);
  int*   srcl  = (int*)alloc((size_t)TOT_E * 4);

  const int NB_N = (NN + 255) / 256;
  const int NB_E = (EE + 255) / 256;
  const int GB   = (NN + 63) / 64;
  const int WB   = (NN + 3) / 4;
  const int CB   = (NN + 31) / 32;

  // ---- CSR build ----
  k_init_deg<<<NB_N, 256, 0, stream>>>(cur);
  k_count<<<NB_E, 256, 0, stream>>>(ei + EE, cur);
  k_scan1<<<NB_N, 256, 0, stream>>>(cur, rowp, blk);
  k_scan2<<<1, 256, 0, stream>>>(blk, NB_N);
  k_scan3<<<NB_N, 256, 0, stream>>>(rowp, cur, blk);
  k_fill_edges<<<NB_E, 256, 0, stream>>>(ei, cur, srcl);
  k_fill_loops<<<NB_N, 256, 0, stream>>>(cur, srcl);

  // ---- input BN stats; apply fused into proj GEMM ----
  hipMemsetAsync(stats, 0, 1024, stream);
  k_bn_stats<64><<<256, 256, 0, stream>>>(x, stats);
  k_bn_final<<<1, 128, 0, stream>>>(stats, in_g, in_b, ssb, 64);

  // ---- proj (bn(x) @ W + b, relu) -> hr (buf0); skip -> buf1 ----
  k_gemm128<64, true, true, 1, false><<<GB, 256, 0, stream>>>(x, projW, projb, buf0, ssb);
  k_gemm128<128, true, false, 0, false><<<GB, 256, 0, stream>>>(buf0, skipW, skipb, buf1, nullptr);

  // ---- GAT layer 1 ----
  k_gemm128<128, false, false, 0, true><<<GB, 256, 0, stream>>>(buf0, c1W, nullptr, hb, nullptr);
  k_sc<4><<<WB, 256, 0, stream>>>(hb, c1as, c1ad, scs, scd);
  k_agg<4><<<WB, 256, 0, stream>>>(hb, scs, scd, rowp, srcl, c1b, buf3);
  hipMemsetAsync(stats, 0, 1024, stream);
  k_bn_stats<128><<<256, 256, 0, stream>>>(buf3, stats);
  k_bn_final<<<1, 128, 0, stream>>>(stats, bn1g, bn1b, ssb, 128);

  // ---- GAT layer 2 (bn1+relu fused into A staging) ----
  k_gemm128<128, false, false, 2, true><<<GB, 256, 0, stream>>>(buf3, c2W, nullptr, hb, ssb);
  k_sc<4><<<WB, 256, 0, stream>>>(hb, c2as, c2ad, scs, scd);
  k_agg<4><<<WB, 256, 0, stream>>>(hb, scs, scd, rowp, srcl, c2b, buf0);
  hipMemsetAsync(stats, 0, 1024, stream);
  k_bn_stats<128><<<256, 256, 0, stream>>>(buf0, stats);
  k_bn_final<<<1, 128, 0, stream>>>(stats, bn2g, bn2b, ssb, 128);

  // ---- GAT layer 3 (H=1; bn2+relu fused into A staging) ----
  k_gemm128<128, false, false, 2, true><<<GB, 256, 0, stream>>>(buf0, c3W, nullptr, hb, ssb);
  k_sc<1><<<WB, 256, 0, stream>>>(hb, c3as, c3ad, scs, scd);
  k_agg<1><<<WB, 256, 0, stream>>>(hb, scs, scd, rowp, srcl, c3b, buf3);
  hipMemsetAsync(stats, 0, 1024, stream);
  k_bn_stats<128><<<256, 256, 0, stream>>>(buf3, stats);
  k_bn_final<<<1, 128, 0, stream>>>(stats, bn3g, bn3b, ssb, 128);
  k_bn_apply<128, true, true><<<2048, 256, 0, stream>>>(buf3, ssb, buf1, buf3);

  // ---- classifier head ----
  k_classifier<<<CB, 256, 0, stream>>>(buf3, clsW1, clsb1, clsW2, clsb2, clsW3, clsb3,
                                       confW, confb, out_logits, out_conf);
}

// Round 3
// 520.225 us; speedup vs baseline: 1.5853x; 1.2386x over previous
//
#include <hip/hip_runtime.h>
#include <cstdint>
#include <cstddef>

#define NN 50000
#define EE 800000
#define TOT_E (NN + EE)

typedef __attribute__((ext_vector_type(8))) short short8;
typedef __attribute__((ext_vector_type(4))) float f32x4;

static __device__ __forceinline__ float lrelu(float x) { return x > 0.f ? x : 0.2f * x; }

static __device__ __forceinline__ unsigned short f2bf(float f) {
  union { float f; unsigned u; } v;
  v.f = f;
  unsigned r = v.u + 0x7FFFu + ((v.u >> 16) & 1u);  // RNE
  return (unsigned short)(r >> 16);
}
static __device__ __forceinline__ float bf2f(unsigned short u) {
  union { unsigned u; float f; } v;
  v.u = ((unsigned)u) << 16;
  return v.f;
}
static __device__ __forceinline__ float bf2f_lo(unsigned u) {
  union { unsigned u; float f; } v;
  v.u = u << 16;
  return v.f;
}
static __device__ __forceinline__ float bf2f_hi(unsigned u) {
  union { unsigned u; float f; } v;
  v.u = u & 0xFFFF0000u;
  return v.f;
}

// ============================ CSR build ============================
__global__ void k_init_deg(int* __restrict__ cur) {
  int i = blockIdx.x * blockDim.x + threadIdx.x;
  if (i < NN) cur[i] = 1;
}
__global__ void k_count(const int* __restrict__ dst, int* __restrict__ cur) {
  int i = blockIdx.x * blockDim.x + threadIdx.x;
  if (i < EE) atomicAdd(&cur[dst[i]], 1);
}
__global__ __launch_bounds__(256) void k_scan1(const int* __restrict__ cur,
                                               int* __restrict__ rowp,
                                               int* __restrict__ blk) {
  __shared__ int sh[256];
  int tx = threadIdx.x;
  int i = blockIdx.x * 256 + tx;
  int v = (i < NN) ? cur[i] : 0;
  sh[tx] = v;
  __syncthreads();
  for (int off = 1; off < 256; off <<= 1) {
    int t = (tx >= off) ? sh[tx - off] : 0;
    __syncthreads();
    sh[tx] += t;
    __syncthreads();
  }
  if (i < NN) rowp[i] = sh[tx] - v;
  if (tx == 255) blk[blockIdx.x] = sh[255];
}
__global__ __launch_bounds__(256) void k_scan2(int* __restrict__ blk, int nb) {
  __shared__ int sh[256];
  int tx = threadIdx.x;
  int v = (tx < nb) ? blk[tx] : 0;
  sh[tx] = v;
  __syncthreads();
  for (int off = 1; off < 256; off <<= 1) {
    int t = (tx >= off) ? sh[tx - off] : 0;
    __syncthreads();
    sh[tx] += t;
    __syncthreads();
  }
  blk[tx] = sh[tx] - v;
}
__global__ void k_scan3(int* __restrict__ rowp, int* __restrict__ cur,
                        const int* __restrict__ blk) {
  int i = blockIdx.x * 256 + threadIdx.x;
  if (i < NN) {
    int v = rowp[i] + blk[blockIdx.x];
    rowp[i] = v;
    cur[i] = v;
  }
  if (i == 0) rowp[NN] = TOT_E;
}
__global__ void k_fill_edges(const int* __restrict__ ei, int* __restrict__ cur,
                             int* __restrict__ srcl) {
  int i = blockIdx.x * blockDim.x + threadIdx.x;
  if (i < EE) {
    int s = ei[i];
    int d = ei[EE + i];
    int p = atomicAdd(&cur[d], 1);
    srcl[p] = s;
  }
}
__global__ void k_fill_loops(int* __restrict__ cur, int* __restrict__ srcl) {
  int i = blockIdx.x * blockDim.x + threadIdx.x;
  if (i < NN) {
    int p = atomicAdd(&cur[i], 1);
    srcl[p] = i;
  }
}

// ============================ BatchNorm stats ============================
template <int C>
__global__ __launch_bounds__(256) void k_bn_stats(const float* __restrict__ x,
                                                  float* __restrict__ sums) {
  constexpr int RP = 256 / C;
  int col = threadIdx.x % C;
  int rsub = threadIdx.x / C;
  float s = 0.f, q = 0.f;
  for (int r = blockIdx.x * RP + rsub; r < NN; r += gridDim.x * RP) {
    float v = x[(size_t)r * C + col];
    s += v;
    q += v * v;
  }
  __shared__ float bs[256], bq[256];
  bs[threadIdx.x] = s;
  bq[threadIdx.x] = q;
  __syncthreads();
  if (threadIdx.x < C) {
#pragma unroll
    for (int i = 1; i < RP; ++i) {
      s += bs[threadIdx.x + i * C];
      q += bq[threadIdx.x + i * C];
    }
    atomicAdd(&sums[col], s);
    atomicAdd(&sums[C + col], q);
  }
}
__global__ void k_bn_final(const float* __restrict__ sums, const float* __restrict__ g,
                           const float* __restrict__ b, float* __restrict__ ss, int C) {
  int c = threadIdx.x;
  if (c < C) {
    float invM = 1.f / (float)NN;
    float mu = sums[c] * invM;
    float var = sums[C + c] * invM - mu * mu;
    float sc = g[c] * rsqrtf(var + 1e-5f);
    ss[c] = sc;
    ss[128 + c] = b[c] - mu * sc;  // shift
  }
}

// ============================ weight reorder (fp32 -> bf16 fragment layout) ============
// layout: flat = ((ct*KB + kb)*16 + c)*32 + q*8 + j ; element (k=kb*32+q*8+j, col=ct*16+c)
template <int K, int NT>
__global__ void k_reorder(const float* __restrict__ W, unsigned short* __restrict__ Wr,
                          int Nsrc) {
  constexpr int KB = K / 32;
  int o = blockIdx.x * 256 + threadIdx.x;
  if (o >= NT * 16 * K) return;
  int j = o & 7;
  int tmp = o >> 3;
  int q = tmp & 3; tmp >>= 2;
  int c = tmp & 15; tmp >>= 4;
  int kb = tmp % KB;
  int ct = tmp / KB;
  int k = kb * 32 + q * 8 + j;
  int col = ct * 16 + c;
  Wr[o] = f2bf(W[(size_t)k * Nsrc + col]);
}
// classifier: cols 0..63 = clsW1[128x64], col 64 = confW[128], cols 65..79 = 0
__global__ void k_reorder_cls(const float* __restrict__ W1, const float* __restrict__ cw,
                              unsigned short* __restrict__ Wr) {
  constexpr int KB = 4;  // K=128
  int o = blockIdx.x * 256 + threadIdx.x;
  if (o >= 5 * 16 * 128) return;
  int j = o & 7;
  int tmp = o >> 3;
  int q = tmp & 3; tmp >>= 2;
  int c = tmp & 15; tmp >>= 4;
  int kb = tmp % KB;
  int ct = tmp / KB;
  int k = kb * 32 + q * 8 + j;
  int col = ct * 16 + c;
  float v = 0.f;
  if (col < 64) v = W1[(size_t)k * 64 + col];
  else if (col == 64) v = cw[k];
  Wr[o] = f2bf(v);
}

// ============================ MFMA GEMM ============================
// C[NN x NT*16] = op(A)[NN x K] @ B[K x NT*16]
// ABF: A is bf16 (else fp32).  BN: 0 none, 1 scale/shift, 2 +relu, 3 +skip+relu
// OUTM: 0 f32 out (stride 128), 1 bf16 out (stride 128), 2 classifier (C1 bf16 stride 64 + conf)
template <int K, int NT, int ABF, int BN, int BIAS, int RELU, int OUTM>
__global__ __launch_bounds__(256) void k_mgemm(
    const void* __restrict__ Ain, const unsigned short* __restrict__ Bw,
    const float* __restrict__ bias, const float* __restrict__ bnss,
    const float* __restrict__ skip, const float* __restrict__ confb,
    void* __restrict__ Cout, float* __restrict__ conf) {
  constexpr int KB = K / 32;
  __shared__ __align__(16) unsigned short sm[(8 + NT) * KB * 512];
  const int tid = threadIdx.x;
  const int r0 = blockIdx.x * 128;

  // ---- stage A (8 row-tiles of 16, fragment-order sub-tiles [16][32]) ----
  if (ABF) {
    const unsigned short* A = (const unsigned short*)Ain;
    constexpr int IT = 128 * (K / 8) / 256;
#pragma unroll
    for (int it = 0; it < IT; ++it) {
      int idx = it * 256 + tid;
      int r = idx / (K / 8);
      int k = (idx % (K / 8)) * 8;
      int gr = r0 + r;
      uint4 v = make_uint4(0, 0, 0, 0);
      if (gr < NN) v = *(const uint4*)(A + (size_t)gr * K + k);
      *(uint4*)&sm[((r >> 4) * KB + (k >> 5)) * 512 + (r & 15) * 32 + (k & 31)] = v;
    }
  } else {
    const float* A = (const float*)Ain;
    constexpr int IT = 128 * (K / 4) / 256;
#pragma unroll
    for (int it = 0; it < IT; ++it) {
      int idx = it * 256 + tid;
      int r = idx / (K / 4);
      int k = (idx % (K / 4)) * 4;
      int gr = r0 + r;
      float4 av = make_float4(0.f, 0.f, 0.f, 0.f);
      if (gr < NN) av = *(const float4*)(A + (size_t)gr * K + k);
      if (BN) {
        float4 sc = *(const float4*)(bnss + k);
        float4 sh = *(const float4*)(bnss + 128 + k);
        av.x = av.x * sc.x + sh.x;
        av.y = av.y * sc.y + sh.y;
        av.z = av.z * sc.z + sh.z;
        av.w = av.w * sc.w + sh.w;
        if (BN == 3 && gr < NN) {
          float4 s = *(const float4*)(skip + (size_t)gr * 128 + k);
          av.x += s.x; av.y += s.y; av.z += s.z; av.w += s.w;
        }
        if (BN >= 2) {
          av.x = fmaxf(av.x, 0.f); av.y = fmaxf(av.y, 0.f);
          av.z = fmaxf(av.z, 0.f); av.w = fmaxf(av.w, 0.f);
        }
      }
      ushort4 o;
      o.x = f2bf(av.x); o.y = f2bf(av.y); o.z = f2bf(av.z); o.w = f2bf(av.w);
      *(ushort4*)&sm[((r >> 4) * KB + (k >> 5)) * 512 + (r & 15) * 32 + (k & 31)] = o;
    }
  }
  // ---- stage B (already fragment-ordered in global: straight copy) ----
  {
    constexpr int BW = NT * KB * 512;  // ushorts
#pragma unroll
    for (int it = 0; it < BW / 2048; ++it) {
      int idx = it * 256 + tid;
      *(uint4*)&sm[8 * KB * 512 + idx * 8] = *(const uint4*)(Bw + idx * 8);
    }
  }
  __syncthreads();

  // ---- MFMA ----
  const int lane = tid & 63, wv = tid >> 6;
  const int lr = lane & 15, lg = lane >> 4;
  const int fidx = lr * 32 + lg * 8;  // conflict-free: each lane its own 16B chunk
  f32x4 acc[2][NT];
#pragma unroll
  for (int f = 0; f < 2; ++f)
#pragma unroll
    for (int ct = 0; ct < NT; ++ct) acc[f][ct] = (f32x4){0.f, 0.f, 0.f, 0.f};
#pragma unroll
  for (int kb = 0; kb < KB; ++kb) {
    short8 a0 = *(const short8*)&sm[((wv * 2 + 0) * KB + kb) * 512 + fidx];
    short8 a1 = *(const short8*)&sm[((wv * 2 + 1) * KB + kb) * 512 + fidx];
#pragma unroll
    for (int ct = 0; ct < NT; ++ct) {
      short8 b = *(const short8*)&sm[((8 + ct) * KB + kb) * 512 + fidx];
      acc[0][ct] = __builtin_amdgcn_mfma_f32_16x16x32_bf16(a0, b, acc[0][ct], 0, 0, 0);
      acc[1][ct] = __builtin_amdgcn_mfma_f32_16x16x32_bf16(a1, b, acc[1][ct], 0, 0, 0);
    }
  }

  // ---- epilogue: row = (lane>>4)*4 + r, col = ct*16 + (lane&15) ----
#pragma unroll
  for (int f = 0; f < 2; ++f) {
    int rowb = r0 + (wv * 2 + f) * 16 + lg * 4;
#pragma unroll
    for (int ct = 0; ct < NT; ++ct) {
      int col = ct * 16 + lr;
      if (OUTM == 2) {
        if (col < 64) {
          float bb = bias[col];
#pragma unroll
          for (int r = 0; r < 4; ++r) {
            int gr = rowb + r;
            if (gr < NN)
              ((unsigned short*)Cout)[(size_t)gr * 64 + col] =
                  f2bf(fmaxf(acc[f][ct][r] + bb, 0.f));
          }
        } else if (col == 64) {
          float cb = confb[0];
#pragma unroll
          for (int r = 0; r < 4; ++r) {
            int gr = rowb + r;
            if (gr < NN) conf[gr] = 1.f / (1.f + __expf(-(acc[f][ct][r] + cb)));
          }
        }
      } else {
        float bb = BIAS ? bias[col] : 0.f;
#pragma unroll
        for (int r = 0; r < 4; ++r) {
          int gr = rowb + r;
          if (gr < NN) {
            float o = acc[f][ct][r] + bb;
            if (RELU) o = fmaxf(o, 0.f);
            if (OUTM == 1)
              ((unsigned short*)Cout)[(size_t)gr * 128 + col] = f2bf(o);
            else
              ((float*)Cout)[(size_t)gr * 128 + col] = o;
          }
        }
      }
    }
  }
}

// ============================ attention scores (bf16 h) ============================
template <int H>
__global__ __launch_bounds__(256) void k_sc(const unsigned short* __restrict__ hp,
                                            const float* __restrict__ a_s,
                                            const float* __restrict__ a_d,
                                            float* __restrict__ scs,
                                            float* __restrict__ scd) {
  int lane = threadIdx.x & 63;
  int n = (blockIdx.x * 256 + threadIdx.x) >> 6;
  if (n >= NN) return;
  unsigned u = *(const unsigned*)(hp + (size_t)n * 128 + lane * 2);
  float vx = bf2f_lo(u), vy = bf2f_hi(u);
  const float2* as2 = (const float2*)a_s;
  const float2* ad2 = (const float2*)a_d;
  float2 a = as2[lane];
  float2 d = ad2[lane];
  float ps = vx * a.x + vy * a.y;
  float pd = vx * d.x + vy * d.y;
  constexpr int LPH = 64 / H;
#pragma unroll
  for (int off = 1; off < LPH; off <<= 1) {
    ps += __shfl_xor(ps, off);
    pd += __shfl_xor(pd, off);
  }
  if ((lane & (LPH - 1)) == 0) {
    int h = lane / LPH;
    scs[(size_t)n * H + h] = ps;
    scd[(size_t)n * H + h] = pd;
  }
}

// ============================ GAT aggregation (single pass) ============================
template <int H>
__global__ __launch_bounds__(256) void k_agg(const unsigned short* __restrict__ hp,
                                             const float* __restrict__ scs,
                                             const float* __restrict__ scd,
                                             const int* __restrict__ rowp,
                                             const int* __restrict__ srcl,
                                             const float* __restrict__ bias,
                                             float* __restrict__ out) {
  int lane = threadIdx.x & 63;
  int n = (blockIdx.x * 256 + threadIdx.x) >> 6;
  if (n >= NN) return;
  int half = lane >> 5;
  int l32 = lane & 31;
  int c0 = l32 * 4;
  int hid = (H == 1) ? 0 : (l32 >> 3);
  float sd = scd[(size_t)n * H + hid];
  int beg = rowp[n], end = rowp[n + 1];
  float a0 = 0.f, a1 = 0.f, a2 = 0.f, a3 = 0.f, sw = 0.f;
  for (int k = beg + half; k < end; k += 2) {
    int s = srcl[k];
    float e = lrelu(scs[(size_t)s * H + hid] + sd);
    float w = __expf(e);
    uint2 u = *(const uint2*)(hp + (size_t)s * 128 + c0);
    a0 = fmaf(w, bf2f_lo(u.x), a0);
    a1 = fmaf(w, bf2f_hi(u.x), a1);
    a2 = fmaf(w, bf2f_lo(u.y), a2);
    a3 = fmaf(w, bf2f_hi(u.y), a3);
    sw += w;
  }
  a0 += __shfl_xor(a0, 32);
  a1 += __shfl_xor(a1, 32);
  a2 += __shfl_xor(a2, 32);
  a3 += __shfl_xor(a3, 32);
  sw += __shfl_xor(sw, 32);
  if (half == 0) {
    float inv = 1.f / (sw + 1e-16f);
    float4 bb = *(const float4*)(bias + c0);
    float4 o;
    o.x = a0 * inv + bb.x;
    o.y = a1 * inv + bb.y;
    o.z = a2 * inv + bb.z;
    o.w = a3 * inv + bb.w;
    *(float4*)(out + (size_t)n * 128 + c0) = o;
  }
}

// ============================ classifier tail: c2 -> c3/logits ============================
__global__ __launch_bounds__(256) void k_head2(const unsigned short* __restrict__ C1,
                                               const float* __restrict__ W2,
                                               const float* __restrict__ b2,
                                               const float* __restrict__ W3,
                                               const float* __restrict__ b3,
                                               float* __restrict__ logits) {
  __shared__ float W2s[64 * 32];
  __shared__ float c2s[32 * 32];
  __shared__ unsigned short c1s[32 * 64];
  __shared__ float b2s[32], W3s[64], b3s[2];
  int tid = threadIdx.x;
  for (int i = tid; i < 64 * 32; i += 256) W2s[i] = W2[i];
  if (tid < 64) W3s[tid] = W3[tid];
  if (tid < 32) b2s[tid] = b2[tid];
  if (tid < 2) b3s[tid] = b3[tid];
  int n0 = blockIdx.x * 32;
  {
    // stage 32 rows x 64 bf16 = 2048 ushorts; 8 per thread (uint4)
    size_t base = (size_t)n0 * 64;
    *(uint4*)&c1s[tid * 8] = *(const uint4*)(C1 + base + (size_t)tid * 8);
  }
  __syncthreads();
  int j = tid & 31;
  int g8 = tid >> 5;
#pragma unroll
  for (int g = 0; g < 4; ++g) {
    int node = g * 8 + g8;
    float acc = b2s[j];
#pragma unroll 8
    for (int k = 0; k < 64; ++k) acc = fmaf(bf2f(c1s[node * 64 + k]), W2s[k * 32 + j], acc);
    c2s[node * 32 + j] = fmaxf(acc, 0.f);
  }
  __syncthreads();
  if (tid < 64) {
    int node = tid >> 1, jj = tid & 1;
    float acc = b3s[jj];
#pragma unroll 8
    for (int k = 0; k < 32; ++k) acc = fmaf(c2s[node * 32 + k], W3s[k * 2 + jj], acc);
    int n = n0 + node;
    if (n < NN) logits[(size_t)n * 2 + jj] = acc;
  }
}

// ============================ launch ============================
extern "C" void kernel_launch(void* const* d_in, const int* in_sizes, int n_in,
                              void* d_out, int out_size, void* d_ws, size_t ws_size,
                              hipStream_t stream) {
  (void)in_sizes; (void)n_in; (void)out_size; (void)ws_size;
  const float* x       = (const float*)d_in[0];
  const int*   ei      = (const int*)d_in[1];
  const float* in_g    = (const float*)d_in[2];
  const float* in_b    = (const float*)d_in[3];
  const float* projW   = (const float*)d_in[4];
  const float* projb   = (const float*)d_in[5];
  const float* skipW   = (const float*)d_in[6];
  const float* skipb   = (const float*)d_in[7];
  const float* c1W     = (const float*)d_in[8];
  const float* c1as    = (const float*)d_in[9];
  const float* c1ad    = (const float*)d_in[10];
  const float* c1b     = (const float*)d_in[11];
  const float* bn1g    = (const float*)d_in[12];
  const float* bn1b    = (const float*)d_in[13];
  const float* c2W     = (const float*)d_in[14];
  const float* c2as    = (const float*)d_in[15];
  const float* c2ad    = (const float*)d_in[16];
  const float* c2b     = (const float*)d_in[17];
  const float* bn2g    = (const float*)d_in[18];
  const float* bn2b    = (const float*)d_in[19];
  const float* c3W     = (const float*)d_in[20];
  const float* c3as    = (const float*)d_in[21];
  const float* c3ad    = (const float*)d_in[22];
  const float* c3b     = (const float*)d_in[23];
  const float* bn3g    = (const float*)d_in[24];
  const float* bn3b    = (const float*)d_in[25];
  const float* clsW1   = (const float*)d_in[26];
  const float* clsb1   = (const float*)d_in[27];
  const float* clsW2   = (const float*)d_in[28];
  const float* clsb2   = (const float*)d_in[29];
  const float* clsW3   = (const float*)d_in[30];
  const float* clsb3   = (const float*)d_in[31];
  const float* confW   = (const float*)d_in[32];
  const float* confb   = (const float*)d_in[33];

  float* out_logits = (float*)d_out;
  float* out_conf   = (float*)d_out + (size_t)NN * 2;

  char* p = (char*)d_ws;
  auto alloc = [&](size_t bytes) -> char* {
    char* r = p;
    p += (bytes + 255) & ~(size_t)255;
    return r;
  };
  unsigned short* hr   = (unsigned short*)alloc((size_t)NN * 128 * 2);  // relu(proj) bf16
  float* buf1 = (float*)alloc((size_t)NN * 128 * 4);  // h_skip f32
  float* buf3 = (float*)alloc((size_t)NN * 128 * 4);  // agg1/agg3 out f32
  float* buf0 = (float*)alloc((size_t)NN * 128 * 4);  // agg2 out f32
  unsigned short* hb = (unsigned short*)alloc((size_t)NN * 128 * 2);  // conv out bf16 / C1
  float* scs   = (float*)alloc((size_t)NN * 4 * 4);
  float* scd   = (float*)alloc((size_t)NN * 4 * 4);
  float* stats = (float*)alloc(256 * 4);
  float* ssb   = (float*)alloc(256 * 4);
  int*   rowp  = (int*)alloc((size_t)(NN + 1) * 4);
  int*   cur   = (int*)alloc((size_t)NN * 4);
  int*   blk   = (int*)alloc(256 * 4);
  int*   srcl  = (int*)alloc((size_t)TOT_E * 4);
  unsigned short* wr_proj = (unsigned short*)alloc(64 * 128 * 2);
  unsigned short* wr_skip = (unsigned short*)alloc(128 * 128 * 2);
  unsigned short* wr_c1   = (unsigned short*)alloc(128 * 128 * 2);
  unsigned short* wr_c2   = (unsigned short*)alloc(128 * 128 * 2);
  unsigned short* wr_c3   = (unsigned short*)alloc(128 * 128 * 2);
  unsigned short* wr_cls  = (unsigned short*)alloc(128 * 80 * 2);
  unsigned short* C1 = hb;  // reuse: hb free once agg3 done

  const int NB_N = (NN + 255) / 256;
  const int NB_E = (EE + 255) / 256;
  const int GB   = (NN + 127) / 128;  // 391 mgemm blocks
  const int WB   = (NN + 3) / 4;
  const int CB   = (NN + 31) / 32;

  // ---- weight reorders (one-shot, independent) ----
  k_reorder<64, 8><<<32, 256, 0, stream>>>(projW, wr_proj, 128);
  k_reorder<128, 8><<<64, 256, 0, stream>>>(skipW, wr_skip, 128);
  k_reorder<128, 8><<<64, 256, 0, stream>>>(c1W, wr_c1, 128);
  k_reorder<128, 8><<<64, 256, 0, stream>>>(c2W, wr_c2, 128);
  k_reorder<128, 8><<<64, 256, 0, stream>>>(c3W, wr_c3, 128);
  k_reorder_cls<<<40, 256, 0, stream>>>(clsW1, confW, wr_cls);

  // ---- CSR build ----
  k_init_deg<<<NB_N, 256, 0, stream>>>(cur);
  k_count<<<NB_E, 256, 0, stream>>>(ei + EE, cur);
  k_scan1<<<NB_N, 256, 0, stream>>>(cur, rowp, blk);
  k_scan2<<<1, 256, 0, stream>>>(blk, NB_N);
  k_scan3<<<NB_N, 256, 0, stream>>>(rowp, cur, blk);
  k_fill_edges<<<NB_E, 256, 0, stream>>>(ei, cur, srcl);
  k_fill_loops<<<NB_N, 256, 0, stream>>>(cur, srcl);

  // ---- input BN stats (apply fused into proj staging) ----
  hipMemsetAsync(stats, 0, 1024, stream);
  k_bn_stats<64><<<256, 256, 0, stream>>>(x, stats);
  k_bn_final<<<1, 128, 0, stream>>>(stats, in_g, in_b, ssb, 64);

  // ---- proj: hr = relu(bn(x) @ projW + projb), bf16 ----
  k_mgemm<64, 8, 0, 1, 1, 1, 1><<<GB, 256, 0, stream>>>(
      x, wr_proj, projb, ssb, nullptr, nullptr, hr, nullptr);
  // ---- skip: buf1 = hr @ skipW + skipb, f32 ----
  k_mgemm<128, 8, 1, 0, 1, 0, 0><<<GB, 256, 0, stream>>>(
      hr, wr_skip, skipb, nullptr, nullptr, nullptr, buf1, nullptr);

  // ---- GAT layer 1 ----
  k_mgemm<128, 8, 1, 0, 0, 0, 1><<<GB, 256, 0, stream>>>(
      hr, wr_c1, nullptr, nullptr, nullptr, nullptr, hb, nullptr);
  k_sc<4><<<WB, 256, 0, stream>>>(hb, c1as, c1ad, scs, scd);
  k_agg<4><<<WB, 256, 0, stream>>>(hb, scs, scd, rowp, srcl, c1b, buf3);
  hipMemsetAsync(stats, 0, 1024, stream);
  k_bn_stats<128><<<256, 256, 0, stream>>>(buf3, stats);
  k_bn_final<<<1, 128, 0, stream>>>(stats, bn1g, bn1b, ssb, 128);

  // ---- GAT layer 2 (bn1+relu fused into staging) ----
  k_mgemm<128, 8, 0, 2, 0, 0, 1><<<GB, 256, 0, stream>>>(
      buf3, wr_c2, nullptr, ssb, nullptr, nullptr, hb, nullptr);
  k_sc<4><<<WB, 256, 0, stream>>>(hb, c2as, c2ad, scs, scd);
  k_agg<4><<<WB, 256, 0, stream>>>(hb, scs, scd, rowp, srcl, c2b, buf0);
  hipMemsetAsync(stats, 0, 1024, stream);
  k_bn_stats<128><<<256, 256, 0, stream>>>(buf0, stats);
  k_bn_final<<<1, 128, 0, stream>>>(stats, bn2g, bn2b, ssb, 128);

  // ---- GAT layer 3 (H=1; bn2+relu fused into staging) ----
  k_mgemm<128, 8, 0, 2, 0, 0, 1><<<GB, 256, 0, stream>>>(
      buf0, wr_c3, nullptr, ssb, nullptr, nullptr, hb, nullptr);
  k_sc<1><<<WB, 256, 0, stream>>>(hb, c3as, c3ad, scs, scd);
  k_agg<1><<<WB, 256, 0, stream>>>(hb, scs, scd, rowp, srcl, c3b, buf3);
  hipMemsetAsync(stats, 0, 1024, stream);
  k_bn_stats<128><<<256, 256, 0, stream>>>(buf3, stats);
  k_bn_final<<<1, 128, 0, stream>>>(stats, bn3g, bn3b, ssb, 128);

  // ---- classifier stage 1: h = relu(bn3(buf3)+buf1); C1 = relu(h@W1+b1); conf ----
  k_mgemm<128, 5, 0, 3, 1, 0, 2><<<GB, 256, 0, stream>>>(
      buf3, wr_cls, clsb1, ssb, buf1, confb, C1, out_conf);
  // ---- classifier tail ----
  k_head2<<<CB, 256, 0, stream>>>(C1, clsW2, clsb2, clsW3, clsb3, out_logits);
}

// Round 4
// 400.847 us; speedup vs baseline: 2.0575x; 1.2978x over previous
//
#include <hip/hip_runtime.h>
#include <cstdint>
#include <cstddef>

#define NN 50000
#define EE 800000
#define TOT_E (NN + EE)

typedef __attribute__((ext_vector_type(8))) short short8;
typedef __attribute__((ext_vector_type(4))) float f32x4;

static __device__ __forceinline__ unsigned short f2bf(float f) {
  union { float f; unsigned u; } v;
  v.f = f;
  unsigned r = v.u + 0x7FFFu + ((v.u >> 16) & 1u);  // RNE
  return (unsigned short)(r >> 16);
}
static __device__ __forceinline__ float bf2f(unsigned short u) {
  union { unsigned u; float f; } v;
  v.u = ((unsigned)u) << 16;
  return v.f;
}
static __device__ __forceinline__ float bf2f_lo(unsigned u) {
  union { unsigned u; float f; } v;
  v.u = u << 16;
  return v.f;
}
static __device__ __forceinline__ float bf2f_hi(unsigned u) {
  union { unsigned u; float f; } v;
  v.u = u & 0xFFFF0000u;
  return v.f;
}

// ============================ CSR build ============================
__global__ void k_count(const int* __restrict__ dst, int* __restrict__ cur) {
  int i = blockIdx.x * blockDim.x + threadIdx.x;
  if (i < EE) atomicAdd(&cur[dst[i]], 1);
}
__global__ __launch_bounds__(256) void k_scan1(const int* __restrict__ cur,
                                               int* __restrict__ rowp,
                                               int* __restrict__ blk) {
  __shared__ int sh[256];
  int tx = threadIdx.x;
  int i = blockIdx.x * 256 + tx;
  int v = (i < NN) ? (cur[i] + 1) : 0;  // +1 = self-loop
  sh[tx] = v;
  __syncthreads();
  for (int off = 1; off < 256; off <<= 1) {
    int t = (tx >= off) ? sh[tx - off] : 0;
    __syncthreads();
    sh[tx] += t;
    __syncthreads();
  }
  if (i < NN) rowp[i] = sh[tx] - v;
  if (tx == 255) blk[blockIdx.x] = sh[255];
}
__global__ __launch_bounds__(256) void k_scan2(int* __restrict__ blk, int nb) {
  __shared__ int sh[256];
  int tx = threadIdx.x;
  int v = (tx < nb) ? blk[tx] : 0;
  sh[tx] = v;
  __syncthreads();
  for (int off = 1; off < 256; off <<= 1) {
    int t = (tx >= off) ? sh[tx - off] : 0;
    __syncthreads();
    sh[tx] += t;
    __syncthreads();
  }
  blk[tx] = sh[tx] - v;
}
// also plants the self-loop entry and sets cur to the next free slot
__global__ void k_scan3(int* __restrict__ rowp, int* __restrict__ cur,
                        const int* __restrict__ blk, int* __restrict__ srcl) {
  int i = blockIdx.x * 256 + threadIdx.x;
  if (i < NN) {
    int v = rowp[i] + blk[blockIdx.x];
    rowp[i] = v;
    srcl[v] = i;       // self-loop first (order within segment is irrelevant)
    cur[i] = v + 1;
  }
  if (i == 0) rowp[NN] = TOT_E;
}
__global__ void k_fill_edges(const int* __restrict__ ei, int* __restrict__ cur,
                             int* __restrict__ srcl) {
  int i = blockIdx.x * blockDim.x + threadIdx.x;
  if (i < EE) {
    int s = ei[i];
    int d = ei[EE + i];
    int p = atomicAdd(&cur[d], 1);
    srcl[p] = s;
  }
}

// ============================ BatchNorm stats ============================
template <int C>
__global__ __launch_bounds__(256) void k_bn_stats(const float* __restrict__ x,
                                                  float* __restrict__ sums) {
  constexpr int RP = 256 / C;
  int col = threadIdx.x % C;
  int rsub = threadIdx.x / C;
  float s = 0.f, q = 0.f;
  for (int r = blockIdx.x * RP + rsub; r < NN; r += gridDim.x * RP) {
    float v = x[(size_t)r * C + col];
    s += v;
    q += v * v;
  }
  __shared__ float bs[256], bq[256];
  bs[threadIdx.x] = s;
  bq[threadIdx.x] = q;
  __syncthreads();
  if (threadIdx.x < C) {
#pragma unroll
    for (int i = 1; i < RP; ++i) {
      s += bs[threadIdx.x + i * C];
      q += bq[threadIdx.x + i * C];
    }
    atomicAdd(&sums[col], s);
    atomicAdd(&sums[C + col], q);
  }
}
// bf16 input, C=128 fixed; thread owns 2 adjacent cols, 4 row-subgroups
__global__ __launch_bounds__(256) void k_bn_stats_bf(const unsigned short* __restrict__ x,
                                                     float* __restrict__ sums) {
  int tid = threadIdx.x;
  int c2 = tid & 63;
  int rs = tid >> 6;
  float s0 = 0.f, q0 = 0.f, s1 = 0.f, q1 = 0.f;
  for (int r = blockIdx.x * 4 + rs; r < NN; r += gridDim.x * 4) {
    unsigned u = *(const unsigned*)(x + (size_t)r * 128 + c2 * 2);
    float v0 = bf2f_lo(u), v1 = bf2f_hi(u);
    s0 += v0; q0 += v0 * v0;
    s1 += v1; q1 += v1 * v1;
  }
  __shared__ float b0[256], b1[256], b2[256], b3[256];
  b0[tid] = s0; b1[tid] = q0; b2[tid] = s1; b3[tid] = q1;
  __syncthreads();
  if (tid < 64) {
#pragma unroll
    for (int i = 1; i < 4; ++i) {
      s0 += b0[tid + i * 64]; q0 += b1[tid + i * 64];
      s1 += b2[tid + i * 64]; q1 += b3[tid + i * 64];
    }
    atomicAdd(&sums[2 * tid], s0);
    atomicAdd(&sums[128 + 2 * tid], q0);
    atomicAdd(&sums[2 * tid + 1], s1);
    atomicAdd(&sums[128 + 2 * tid + 1], q1);
  }
}

// ============================ fused weight reorder ============================
// dest layout per region: flat = ((ct*KB + kb)*16 + c)*32 + q*8 + j
// element (k = kb*32+q*8+j, col = ct*16+c)
__global__ void k_reorder_all(const float* __restrict__ projW, const float* __restrict__ skipW,
                              const float* __restrict__ c1W, const float* __restrict__ c2W,
                              const float* __restrict__ c3W, const float* __restrict__ W1,
                              const float* __restrict__ cw, unsigned short* __restrict__ wr) {
  int o = blockIdx.x * 256 + threadIdx.x;
  if (o < 8192) {  // proj: K=64, NT=8
    int off = o;
    int j = off & 7, t = off >> 3;
    int q = t & 3; t >>= 2;
    int c = t & 15; t >>= 4;
    int kb = t & 1, ct = t >> 1;
    int k = kb * 32 + q * 8 + j, col = ct * 16 + c;
    wr[o] = f2bf(projW[(size_t)k * 128 + col]);
  } else if (o < 73728) {  // skip/c1/c2/c3: K=128, NT=8
    int region = (o - 8192) >> 14;
    int off = (o - 8192) & 16383;
    const float* W = region == 0 ? skipW : region == 1 ? c1W : region == 2 ? c2W : c3W;
    int j = off & 7, t = off >> 3;
    int q = t & 3; t >>= 2;
    int c = t & 15; t >>= 4;
    int kb = t & 3, ct = t >> 2;
    int k = kb * 32 + q * 8 + j, col = ct * 16 + c;
    wr[o] = f2bf(W[(size_t)k * 128 + col]);
  } else if (o < 83968) {  // cls: K=128, NT=5 (cols 0..63 W1, 64 confW, 65..79 zero)
    int off = o - 73728;
    int j = off & 7, t = off >> 3;
    int q = t & 3; t >>= 2;
    int c = t & 15; t >>= 4;
    int kb = t & 3, ct = t >> 2;
    int k = kb * 32 + q * 8 + j, col = ct * 16 + c;
    float v = 0.f;
    if (col < 64) v = W1[(size_t)k * 64 + col];
    else if (col == 64) v = cw[k];
    wr[o] = f2bf(v);
  }
}

// ============================ MFMA GEMM ============================
// C[NN x NT*16] = op(A)[NN x K] @ B[K x NT*16]
// ABF: A bf16 (else fp32). BN: 0 none, 1 sc/sh, 2 +relu, 3 +skip+relu (bn computed
// in-block from sums/gamma/beta). OUTM: 1 bf16 out stride 128, 2 classifier.
// SCH: 0 off, 1/4 = compute GAT attention scores (scs/scd) in epilogue.
template <int K, int NT, int ABF, int BN, int BIAS, int RELU, int OUTM, int SCH>
__global__ __launch_bounds__(256) void k_mgemm(
    const void* __restrict__ Ain, const unsigned short* __restrict__ Bw,
    const float* __restrict__ bias,
    const float* __restrict__ bnsums, const float* __restrict__ bng,
    const float* __restrict__ bnb,
    const unsigned short* __restrict__ skip,
    const float* __restrict__ a_s, const float* __restrict__ a_d,
    const float* __restrict__ confb,
    void* __restrict__ Cout, float* __restrict__ conf,
    float* __restrict__ scs, float* __restrict__ scd) {
  constexpr int KB = K / 32;
  __shared__ __align__(16) unsigned short sm[(8 + NT) * KB * 512];
  __shared__ float bnsc[128], bnsh[128];
  const int tid = threadIdx.x;
  const int r0 = blockIdx.x * 128;

  if constexpr (BN) {
    if (tid < K) {
      float invM = 1.f / (float)NN;
      float mu = bnsums[tid] * invM;
      float var = bnsums[K + tid] * invM - mu * mu;
      float sc = bng[tid] * rsqrtf(var + 1e-5f);
      bnsc[tid] = sc;
      bnsh[tid] = bnb[tid] - mu * sc;
    }
    __syncthreads();
  }

  // ---- stage A ----
  if constexpr (ABF) {
    const unsigned short* A = (const unsigned short*)Ain;
    constexpr int IT = 128 * (K / 8) / 256;
#pragma unroll
    for (int it = 0; it < IT; ++it) {
      int idx = it * 256 + tid;
      int r = idx / (K / 8);
      int k = (idx % (K / 8)) * 8;
      int gr = r0 + r;
      union { uint4 u4; unsigned short us[8]; } v;
      v.u4 = make_uint4(0, 0, 0, 0);
      if (gr < NN) v.u4 = *(const uint4*)(A + (size_t)gr * K + k);
      if constexpr (BN) {
        union { uint4 u4; unsigned short us[8]; } sv;
        if (BN == 3) {
          sv.u4 = make_uint4(0, 0, 0, 0);
          if (gr < NN) sv.u4 = *(const uint4*)(skip + (size_t)gr * 128 + k);
        }
#pragma unroll
        for (int j = 0; j < 8; ++j) {
          float f = bf2f(v.us[j]) * bnsc[k + j] + bnsh[k + j];
          if (BN == 3) f += bf2f(sv.us[j]);
          if (BN >= 2) f = fmaxf(f, 0.f);
          v.us[j] = f2bf(f);
        }
      }
      *(uint4*)&sm[((r >> 4) * KB + (k >> 5)) * 512 + (r & 15) * 32 + (k & 31)] = v.u4;
    }
  } else {
    const float* A = (const float*)Ain;
    constexpr int IT = 128 * (K / 4) / 256;
#pragma unroll
    for (int it = 0; it < IT; ++it) {
      int idx = it * 256 + tid;
      int r = idx / (K / 4);
      int k = (idx % (K / 4)) * 4;
      int gr = r0 + r;
      float4 av = make_float4(0.f, 0.f, 0.f, 0.f);
      if (gr < NN) av = *(const float4*)(A + (size_t)gr * K + k);
      if constexpr (BN) {
        av.x = av.x * bnsc[k + 0] + bnsh[k + 0];
        av.y = av.y * bnsc[k + 1] + bnsh[k + 1];
        av.z = av.z * bnsc[k + 2] + bnsh[k + 2];
        av.w = av.w * bnsc[k + 3] + bnsh[k + 3];
        if (BN >= 2) {
          av.x = fmaxf(av.x, 0.f); av.y = fmaxf(av.y, 0.f);
          av.z = fmaxf(av.z, 0.f); av.w = fmaxf(av.w, 0.f);
        }
      }
      ushort4 o;
      o.x = f2bf(av.x); o.y = f2bf(av.y); o.z = f2bf(av.z); o.w = f2bf(av.w);
      *(ushort4*)&sm[((r >> 4) * KB + (k >> 5)) * 512 + (r & 15) * 32 + (k & 31)] = o;
    }
  }
  // ---- stage B (fragment-ordered in global) ----
  {
    constexpr int BW = NT * KB * 512;
#pragma unroll
    for (int it = 0; it < BW / 2048; ++it) {
      int idx = it * 256 + tid;
      *(uint4*)&sm[8 * KB * 512 + idx * 8] = *(const uint4*)(Bw + idx * 8);
    }
  }
  __syncthreads();

  // ---- MFMA ----
  const int lane = tid & 63, wv = tid >> 6;
  const int lr = lane & 15, lg = lane >> 4;
  const int fidx = lr * 32 + lg * 8;
  f32x4 acc[2][NT];
#pragma unroll
  for (int f = 0; f < 2; ++f)
#pragma unroll
    for (int ct = 0; ct < NT; ++ct) acc[f][ct] = (f32x4){0.f, 0.f, 0.f, 0.f};
#pragma unroll
  for (int kb = 0; kb < KB; ++kb) {
    short8 a0 = *(const short8*)&sm[((wv * 2 + 0) * KB + kb) * 512 + fidx];
    short8 a1 = *(const short8*)&sm[((wv * 2 + 1) * KB + kb) * 512 + fidx];
#pragma unroll
    for (int ct = 0; ct < NT; ++ct) {
      short8 b = *(const short8*)&sm[((8 + ct) * KB + kb) * 512 + fidx];
      acc[0][ct] = __builtin_amdgcn_mfma_f32_16x16x32_bf16(a0, b, acc[0][ct], 0, 0, 0);
      acc[1][ct] = __builtin_amdgcn_mfma_f32_16x16x32_bf16(a1, b, acc[1][ct], 0, 0, 0);
    }
  }

  // ---- fused attention scores (per-head dots over the accumulator) ----
  if constexpr (SCH > 0) {
    constexpr int NH = (SCH == 1) ? 1 : 4;
    float asv[NT], adv[NT];
#pragma unroll
    for (int ct = 0; ct < NT; ++ct) {
      asv[ct] = a_s[ct * 16 + lr];
      adv[ct] = a_d[ct * 16 + lr];
    }
    float ps[2][4][NH], pd[2][4][NH];
#pragma unroll
    for (int f = 0; f < 2; ++f)
#pragma unroll
      for (int r = 0; r < 4; ++r)
#pragma unroll
        for (int h = 0; h < NH; ++h) { ps[f][r][h] = 0.f; pd[f][r][h] = 0.f; }
#pragma unroll
    for (int f = 0; f < 2; ++f)
#pragma unroll
      for (int ct = 0; ct < NT; ++ct) {
        int h = (NH == 1) ? 0 : (ct >> 1);
#pragma unroll
        for (int r = 0; r < 4; ++r) {
          ps[f][r][h] = fmaf(acc[f][ct][r], asv[ct], ps[f][r][h]);
          pd[f][r][h] = fmaf(acc[f][ct][r], adv[ct], pd[f][r][h]);
        }
      }
#pragma unroll
    for (int off = 1; off < 16; off <<= 1)
#pragma unroll
      for (int f = 0; f < 2; ++f)
#pragma unroll
        for (int r = 0; r < 4; ++r)
#pragma unroll
          for (int h = 0; h < NH; ++h) {
            ps[f][r][h] += __shfl_xor(ps[f][r][h], off);
            pd[f][r][h] += __shfl_xor(pd[f][r][h], off);
          }
    if (lr == 0) {
#pragma unroll
      for (int f = 0; f < 2; ++f) {
        int rowb = r0 + (wv * 2 + f) * 16 + lg * 4;
#pragma unroll
        for (int r = 0; r < 4; ++r) {
          int gr = rowb + r;
          if (gr < NN) {
            if (NH == 4) {
              float4 vs = make_float4(ps[f][r][0], ps[f][r][1], ps[f][r][2], ps[f][r][3]);
              float4 vd = make_float4(pd[f][r][0], pd[f][r][1], pd[f][r][2], pd[f][r][3]);
              *(float4*)(scs + (size_t)gr * 4) = vs;
              *(float4*)(scd + (size_t)gr * 4) = vd;
            } else {
              scs[gr] = ps[f][r][0];
              scd[gr] = pd[f][r][0];
            }
          }
        }
      }
    }
  }

  // ---- epilogue ----
#pragma unroll
  for (int f = 0; f < 2; ++f) {
    int rowb = r0 + (wv * 2 + f) * 16 + lg * 4;
#pragma unroll
    for (int ct = 0; ct < NT; ++ct) {
      int col = ct * 16 + lr;
      if constexpr (OUTM == 2) {
        if (col < 64) {
          float bb = bias[col];
#pragma unroll
          for (int r = 0; r < 4; ++r) {
            int gr = rowb + r;
            if (gr < NN)
              ((unsigned short*)Cout)[(size_t)gr * 64 + col] =
                  f2bf(fmaxf(acc[f][ct][r] + bb, 0.f));
          }
        } else if (col == 64) {
          float cb = confb[0];
#pragma unroll
          for (int r = 0; r < 4; ++r) {
            int gr = rowb + r;
            if (gr < NN) conf[gr] = 1.f / (1.f + __expf(-(acc[f][ct][r] + cb)));
          }
        }
      } else {
        float bb = BIAS ? bias[col] : 0.f;
#pragma unroll
        for (int r = 0; r < 4; ++r) {
          int gr = rowb + r;
          if (gr < NN) {
            float o = acc[f][ct][r] + bb;
            if (RELU) o = fmaxf(o, 0.f);
            ((unsigned short*)Cout)[(size_t)gr * 128 + col] = f2bf(o);
          }
        }
      }
    }
  }
}

// ============================ GAT aggregation ============================
// One wave per dst node, quarter-wave edge split: 4 edges in flight, 16 lanes x
// 8 bf16 channels (uint4) per edge. softmax(e-m)==softmax(e): no max pass.
template <int H>
__global__ __launch_bounds__(256) void k_agg(const unsigned short* __restrict__ hp,
                                             const float* __restrict__ scs,
                                             const float* __restrict__ scd,
                                             const int* __restrict__ rowp,
                                             const int* __restrict__ srcl,
                                             const float* __restrict__ bias,
                                             unsigned short* __restrict__ out) {
  int lane = threadIdx.x & 63;
  int n = (blockIdx.x * 256 + threadIdx.x) >> 6;
  if (n >= NN) return;
  int q = lane >> 4;
  int l16 = lane & 15;
  int c0 = l16 * 8;
  int hid = (H == 1) ? 0 : (l16 >> 2);
  float sd = scd[(size_t)n * H + hid];
  int beg = rowp[n], end = rowp[n + 1];
  float a[8];
#pragma unroll
  for (int i = 0; i < 8; ++i) a[i] = 0.f;
  float sw = 0.f;
  int k = beg + q;
  int s_next = (k < end) ? srcl[k] : 0;
  for (; k < end; k += 4) {
    int s = s_next;
    int kn = k + 4;
    if (kn < end) s_next = srcl[kn];
    float e = scs[(size_t)s * H + hid] + sd;
    e = fmaxf(e, 0.f) + 0.2f * fminf(e, 0.f);  // leaky relu
    float w = __expf(e);
    uint4 u = *(const uint4*)(hp + (size_t)s * 128 + c0);
    a[0] = fmaf(w, bf2f_lo(u.x), a[0]);
    a[1] = fmaf(w, bf2f_hi(u.x), a[1]);
    a[2] = fmaf(w, bf2f_lo(u.y), a[2]);
    a[3] = fmaf(w, bf2f_hi(u.y), a[3]);
    a[4] = fmaf(w, bf2f_lo(u.z), a[4]);
    a[5] = fmaf(w, bf2f_hi(u.z), a[5]);
    a[6] = fmaf(w, bf2f_lo(u.w), a[6]);
    a[7] = fmaf(w, bf2f_hi(u.w), a[7]);
    sw += w;
  }
#pragma unroll
  for (int i = 0; i < 8; ++i) {
    a[i] += __shfl_xor(a[i], 16);
    a[i] += __shfl_xor(a[i], 32);
  }
  sw += __shfl_xor(sw, 16);
  sw += __shfl_xor(sw, 32);
  if (q == 0) {
    float inv = 1.f / (sw + 1e-16f);
    float4 bb0 = *(const float4*)(bias + c0);
    float4 bb1 = *(const float4*)(bias + c0 + 4);
    unsigned w0 = (unsigned)f2bf(a[0] * inv + bb0.x) | ((unsigned)f2bf(a[1] * inv + bb0.y) << 16);
    unsigned w1 = (unsigned)f2bf(a[2] * inv + bb0.z) | ((unsigned)f2bf(a[3] * inv + bb0.w) << 16);
    unsigned w2 = (unsigned)f2bf(a[4] * inv + bb1.x) | ((unsigned)f2bf(a[5] * inv + bb1.y) << 16);
    unsigned w3 = (unsigned)f2bf(a[6] * inv + bb1.z) | ((unsigned)f2bf(a[7] * inv + bb1.w) << 16);
    uint4 o = make_uint4(w0, w1, w2, w3);
    *(uint4*)(out + (size_t)n * 128 + c0) = o;
  }
}

// ============================ classifier tail: c2 -> c3/logits ============================
__global__ __launch_bounds__(256) void k_head2(const unsigned short* __restrict__ C1,
                                               const float* __restrict__ W2,
                                               const float* __restrict__ b2,
                                               const float* __restrict__ W3,
                                               const float* __restrict__ b3,
                                               float* __restrict__ logits) {
  __shared__ float W2s[64 * 32];
  __shared__ float c2s[32 * 32];
  __shared__ unsigned short c1s[32 * 64];
  __shared__ float b2s[32], W3s[64], b3s[2];
  int tid = threadIdx.x;
  for (int i = tid; i < 64 * 32; i += 256) W2s[i] = W2[i];
  if (tid < 64) W3s[tid] = W3[tid];
  if (tid < 32) b2s[tid] = b2[tid];
  if (tid < 2) b3s[tid] = b3[tid];
  int n0 = blockIdx.x * 32;
  {
    size_t base = (size_t)n0 * 64;
    *(uint4*)&c1s[tid * 8] = *(const uint4*)(C1 + base + (size_t)tid * 8);
  }
  __syncthreads();
  int j = tid & 31;
  int g8 = tid >> 5;
#pragma unroll
  for (int g = 0; g < 4; ++g) {
    int node = g * 8 + g8;
    float acc = b2s[j];
#pragma unroll 8
    for (int k = 0; k < 64; ++k) acc = fmaf(bf2f(c1s[node * 64 + k]), W2s[k * 32 + j], acc);
    c2s[node * 32 + j] = fmaxf(acc, 0.f);
  }
  __syncthreads();
  if (tid < 64) {
    int node = tid >> 1, jj = tid & 1;
    float acc = b3s[jj];
#pragma unroll 8
    for (int k = 0; k < 32; ++k) acc = fmaf(c2s[node * 32 + k], W3s[k * 2 + jj], acc);
    int n = n0 + node;
    if (n < NN) logits[(size_t)n * 2 + jj] = acc;
  }
}

// ============================ launch ============================
extern "C" void kernel_launch(void* const* d_in, const int* in_sizes, int n_in,
                              void* d_out, int out_size, void* d_ws, size_t ws_size,
                              hipStream_t stream) {
  (void)in_sizes; (void)n_in; (void)out_size; (void)ws_size;
  const float* x       = (const float*)d_in[0];
  const int*   ei      = (const int*)d_in[1];
  const float* in_g    = (const float*)d_in[2];
  const float* in_b    = (const float*)d_in[3];
  const float* projW   = (const float*)d_in[4];
  const float* projb   = (const float*)d_in[5];
  const float* skipW   = (const float*)d_in[6];
  const float* skipb   = (const float*)d_in[7];
  const float* c1W     = (const float*)d_in[8];
  const float* c1as    = (const float*)d_in[9];
  const float* c1ad    = (const float*)d_in[10];
  const float* c1b     = (const float*)d_in[11];
  const float* bn1g    = (const float*)d_in[12];
  const float* bn1b    = (const float*)d_in[13];
  const float* c2W     = (const float*)d_in[14];
  const float* c2as    = (const float*)d_in[15];
  const float* c2ad    = (const float*)d_in[16];
  const float* c2b     = (const float*)d_in[17];
  const float* bn2g    = (const float*)d_in[18];
  const float* bn2b    = (const float*)d_in[19];
  const float* c3W     = (const float*)d_in[20];
  const float* c3as    = (const float*)d_in[21];
  const float* c3ad    = (const float*)d_in[22];
  const float* c3b     = (const float*)d_in[23];
  const float* bn3g    = (const float*)d_in[24];
  const float* bn3b    = (const float*)d_in[25];
  const float* clsW1   = (const float*)d_in[26];
  const float* clsb1   = (const float*)d_in[27];
  const float* clsW2   = (const float*)d_in[28];
  const float* clsb2   = (const float*)d_in[29];
  const float* clsW3   = (const float*)d_in[30];
  const float* clsb3   = (const float*)d_in[31];
  const float* confW   = (const float*)d_in[32];
  const float* confb   = (const float*)d_in[33];

  float* out_logits = (float*)d_out;
  float* out_conf   = (float*)d_out + (size_t)NN * 2;

  char* p = (char*)d_ws;
  auto alloc = [&](size_t bytes) -> char* {
    char* r = p;
    p += (bytes + 255) & ~(size_t)255;
    return r;
  };
  unsigned short* hr  = (unsigned short*)alloc((size_t)NN * 128 * 2);  // relu(proj)
  unsigned short* hsk = (unsigned short*)alloc((size_t)NN * 128 * 2);  // h_skip
  unsigned short* hb  = (unsigned short*)alloc((size_t)NN * 128 * 2);  // conv h / C1
  unsigned short* agA = (unsigned short*)alloc((size_t)NN * 128 * 2);  // agg out (L1, L3)
  unsigned short* agB = (unsigned short*)alloc((size_t)NN * 128 * 2);  // agg out (L2)
  float* scs   = (float*)alloc((size_t)NN * 4 * 4);
  float* scd   = (float*)alloc((size_t)NN * 4 * 4);
  float* stats = (float*)alloc(4 * 256 * 4);
  int*   rowp  = (int*)alloc((size_t)(NN + 1) * 4);
  int*   cur   = (int*)alloc((size_t)NN * 4);
  int*   blk   = (int*)alloc(256 * 4);
  int*   srcl  = (int*)alloc((size_t)TOT_E * 4);
  unsigned short* wr = (unsigned short*)alloc(83968 * 2);
  unsigned short* wr_proj = wr;
  unsigned short* wr_skip = wr + 8192;
  unsigned short* wr_c1   = wr + 24576;
  unsigned short* wr_c2   = wr + 40960;
  unsigned short* wr_c3   = wr + 57344;
  unsigned short* wr_cls  = wr + 73728;
  unsigned short* C1 = hb;  // reuse after L3 agg

  const int NB_N = (NN + 255) / 256;
  const int NB_E = (EE + 255) / 256;
  const int GB   = (NN + 127) / 128;
  const int WB   = (NN + 3) / 4;
  const int CB   = (NN + 31) / 32;

  k_reorder_all<<<328, 256, 0, stream>>>(projW, skipW, c1W, c2W, c3W, clsW1, confW, wr);
  hipMemsetAsync(cur, 0, (size_t)NN * 4, stream);
  hipMemsetAsync(stats, 0, 4 * 256 * 4, stream);

  // ---- CSR build ----
  k_count<<<NB_E, 256, 0, stream>>>(ei + EE, cur);
  k_scan1<<<NB_N, 256, 0, stream>>>(cur, rowp, blk);
  k_scan2<<<1, 256, 0, stream>>>(blk, NB_N);
  k_scan3<<<NB_N, 256, 0, stream>>>(rowp, cur, blk, srcl);
  k_fill_edges<<<NB_E, 256, 0, stream>>>(ei, cur, srcl);

  // ---- input BN stats ----
  k_bn_stats<64><<<256, 256, 0, stream>>>(x, stats);

  // ---- proj: hr = relu(bn(x) @ projW + b) ----
  k_mgemm<64, 8, 0, 1, 1, 1, 1, 0><<<GB, 256, 0, stream>>>(
      x, wr_proj, projb, stats, in_g, in_b, nullptr, nullptr, nullptr, nullptr,
      hr, nullptr, nullptr, nullptr);
  // ---- skip: hsk = hr @ skipW + b ----
  k_mgemm<128, 8, 1, 0, 1, 0, 1, 0><<<GB, 256, 0, stream>>>(
      hr, wr_skip, skipb, nullptr, nullptr, nullptr, nullptr, nullptr, nullptr, nullptr,
      hsk, nullptr, nullptr, nullptr);

  // ---- GAT layer 1 ----
  k_mgemm<128, 8, 1, 0, 0, 0, 1, 4><<<GB, 256, 0, stream>>>(
      hr, wr_c1, nullptr, nullptr, nullptr, nullptr, nullptr, c1as, c1ad, nullptr,
      hb, nullptr, scs, scd);
  k_agg<4><<<WB, 256, 0, stream>>>(hb, scs, scd, rowp, srcl, c1b, agA);
  k_bn_stats_bf<<<256, 256, 0, stream>>>(agA, stats + 256);

  // ---- GAT layer 2 (bn1+relu fused into A staging) ----
  k_mgemm<128, 8, 1, 2, 0, 0, 1, 4><<<GB, 256, 0, stream>>>(
      agA, wr_c2, nullptr, stats + 256, bn1g, bn1b, nullptr, c2as, c2ad, nullptr,
      hb, nullptr, scs, scd);
  k_agg<4><<<WB, 256, 0, stream>>>(hb, scs, scd, rowp, srcl, c2b, agB);
  k_bn_stats_bf<<<256, 256, 0, stream>>>(agB, stats + 512);

  // ---- GAT layer 3 (H=1; bn2+relu fused) ----
  k_mgemm<128, 8, 1, 2, 0, 0, 1, 1><<<GB, 256, 0, stream>>>(
      agB, wr_c3, nullptr, stats + 512, bn2g, bn2b, nullptr, c3as, c3ad, nullptr,
      hb, nullptr, scs, scd);
  k_agg<1><<<WB, 256, 0, stream>>>(hb, scs, scd, rowp, srcl, c3b, agA);
  k_bn_stats_bf<<<256, 256, 0, stream>>>(agA, stats + 768);

  // ---- classifier stage 1: relu(bn3(agA)+hsk) @ [W1|confW] ----
  k_mgemm<128, 5, 1, 3, 1, 0, 2, 0><<<GB, 256, 0, stream>>>(
      agA, wr_cls, clsb1, stats + 768, bn3g, bn3b, hsk, nullptr, nullptr, confb,
      C1, out_conf, nullptr, nullptr);
  // ---- classifier tail ----
  k_head2<<<CB, 256, 0, stream>>>(C1, clsW2, clsb2, clsW3, clsb3, out_logits);
}

// Round 5
// 330.053 us; speedup vs baseline: 2.4988x; 1.2145x over previous
//
#include <hip/hip_runtime.h>
#include <cstdint>
#include <cstddef>

#define NN 50000
#define EE 800000
#define TOT_E (NN + EE)
#define NBK 391      // buckets of 128 dst nodes
#define BCAP 2560    // bucket capacity (mean 2048, sigma ~45 -> 11 sigma headroom)

typedef __attribute__((ext_vector_type(8))) short short8;
typedef __attribute__((ext_vector_type(4))) float f32x4;

static __device__ __forceinline__ unsigned short f2bf(float f) {
  union { float f; unsigned u; } v;
  v.f = f;
  unsigned r = v.u + 0x7FFFu + ((v.u >> 16) & 1u);  // RNE
  return (unsigned short)(r >> 16);
}
static __device__ __forceinline__ float bf2f(unsigned short u) {
  union { unsigned u; float f; } v;
  v.u = ((unsigned)u) << 16;
  return v.f;
}
static __device__ __forceinline__ float bf2f_lo(unsigned u) {
  union { unsigned u; float f; } v;
  v.u = u << 16;
  return v.f;
}
static __device__ __forceinline__ float bf2f_hi(unsigned u) {
  union { unsigned u; float f; } v;
  v.u = u & 0xFFFF0000u;
  return v.f;
}

// ============================ CSR build: bucket binning ============================
// pass A: bin edges by dst>>7 into per-bucket regions; packed src | dstloc<<16
__global__ __launch_bounds__(512) void k_bin(const int* __restrict__ ei,
                                             int* __restrict__ gpos,
                                             unsigned* __restrict__ binned) {
  __shared__ int cnt[512];
  __shared__ int base[512];
  int tx = threadIdx.x;
  cnt[tx] = 0;
  __syncthreads();
  int e0 = blockIdx.x * 3125;
  int e1 = e0 + 3125;
  if (e1 > EE) e1 = EE;
  for (int i = e0 + tx; i < e1; i += 512) {
    int d = ei[EE + i];
    atomicAdd(&cnt[d >> 7], 1);
  }
  __syncthreads();
  if (tx < NBK) {
    int c = cnt[tx];
    base[tx] = c ? atomicAdd(&gpos[tx], c) : 0;
    cnt[tx] = 0;
  }
  __syncthreads();
  for (int i = e0 + tx; i < e1; i += 512) {
    int s = ei[i];
    int d = ei[EE + i];
    int b = d >> 7;
    int slot = base[b] + atomicAdd(&cnt[b], 1);
    if (slot < BCAP) binned[(size_t)b * BCAP + slot] = (unsigned)s | ((unsigned)(d & 127) << 16);
  }
}
// scan bucket totals (+self-loops) -> per-bucket edge base
__global__ __launch_bounds__(512) void k_bscan(const int* __restrict__ gpos,
                                               int* __restrict__ ebase,
                                               int* __restrict__ rowp) {
  __shared__ int sh[512];
  int tx = threadIdx.x;
  int v = 0;
  if (tx < NBK) {
    int nodes = NN - (tx << 7);
    if (nodes > 128) nodes = 128;
    int g = gpos[tx];
    if (g > BCAP) g = BCAP;
    v = g + nodes;
  }
  sh[tx] = v;
  __syncthreads();
  for (int off = 1; off < 512; off <<= 1) {
    int t = (tx >= off) ? sh[tx - off] : 0;
    __syncthreads();
    sh[tx] += t;
    __syncthreads();
  }
  if (tx < NBK) ebase[tx] = sh[tx] - v;
  if (tx == NBK - 1) rowp[NN] = sh[tx];
}
// per bucket: per-node counts -> rowp, self-loop, scatter srcl (block-local region)
__global__ __launch_bounds__(256) void k_bucket(const unsigned* __restrict__ binned,
                                                const int* __restrict__ gpos,
                                                const int* __restrict__ ebase,
                                                int* __restrict__ rowp,
                                                int* __restrict__ srcl) {
  __shared__ int cnt[128], offs[128], cur[128];
  int b = blockIdx.x, tid = threadIdx.x;
  int n0 = b << 7;
  int nodes = NN - n0;
  if (nodes > 128) nodes = 128;
  int ne = gpos[b];
  if (ne > BCAP) ne = BCAP;
  int eb = ebase[b];
  if (tid < 128) cnt[tid] = (tid < nodes) ? 1 : 0;  // 1 = self-loop
  __syncthreads();
  const unsigned* bb = binned + (size_t)b * BCAP;
  for (int i = tid; i < ne; i += 256) atomicAdd(&cnt[bb[i] >> 16], 1);
  __syncthreads();
  if (tid < 128) offs[tid] = cnt[tid];
  __syncthreads();
  for (int o = 1; o < 128; o <<= 1) {
    int t = (tid < 128 && tid >= o) ? offs[tid - o] : 0;
    __syncthreads();
    if (tid < 128) offs[tid] += t;
    __syncthreads();
  }
  if (tid < 128 && tid < nodes) {
    int ex = offs[tid] - cnt[tid];
    rowp[n0 + tid] = eb + ex;
    srcl[eb + ex] = n0 + tid;  // self-loop first (segment order irrelevant)
    cur[tid] = ex + 1;
  }
  __syncthreads();
  for (int i = tid; i < ne; i += 256) {
    unsigned e = bb[i];
    int r = atomicAdd(&cur[e >> 16], 1);
    srcl[eb + r] = (int)(e & 0xFFFFu);
  }
}

// ============================ BatchNorm stats ============================
template <int C>
__global__ __launch_bounds__(256) void k_bn_stats(const float* __restrict__ x,
                                                  float* __restrict__ sums) {
  constexpr int RP = 256 / C;
  int col = threadIdx.x % C;
  int rsub = threadIdx.x / C;
  float s = 0.f, q = 0.f;
  for (int r = blockIdx.x * RP + rsub; r < NN; r += gridDim.x * RP) {
    float v = x[(size_t)r * C + col];
    s += v;
    q += v * v;
  }
  __shared__ float bs[256], bq[256];
  bs[threadIdx.x] = s;
  bq[threadIdx.x] = q;
  __syncthreads();
  if (threadIdx.x < C) {
#pragma unroll
    for (int i = 1; i < RP; ++i) {
      s += bs[threadIdx.x + i * C];
      q += bq[threadIdx.x + i * C];
    }
    atomicAdd(&sums[col], s);
    atomicAdd(&sums[C + col], q);
  }
}
// bf16 input, C=128 fixed
__global__ __launch_bounds__(256) void k_bn_stats_bf(const unsigned short* __restrict__ x,
                                                     float* __restrict__ sums) {
  int tid = threadIdx.x;
  int c2 = tid & 63;
  int rs = tid >> 6;
  float s0 = 0.f, q0 = 0.f, s1 = 0.f, q1 = 0.f;
  for (int r = blockIdx.x * 4 + rs; r < NN; r += gridDim.x * 4) {
    unsigned u = *(const unsigned*)(x + (size_t)r * 128 + c2 * 2);
    float v0 = bf2f_lo(u), v1 = bf2f_hi(u);
    s0 += v0; q0 += v0 * v0;
    s1 += v1; q1 += v1 * v1;
  }
  __shared__ float b0[256], b1[256], b2[256], b3[256];
  b0[tid] = s0; b1[tid] = q0; b2[tid] = s1; b3[tid] = q1;
  __syncthreads();
  if (tid < 64) {
#pragma unroll
    for (int i = 1; i < 4; ++i) {
      s0 += b0[tid + i * 64]; q0 += b1[tid + i * 64];
      s1 += b2[tid + i * 64]; q1 += b3[tid + i * 64];
    }
    atomicAdd(&sums[2 * tid], s0);
    atomicAdd(&sums[128 + 2 * tid], q0);
    atomicAdd(&sums[2 * tid + 1], s1);
    atomicAdd(&sums[128 + 2 * tid + 1], q1);
  }
}

// ============================ fused weight reorder ============================
__global__ void k_reorder_all(const float* __restrict__ projW, const float* __restrict__ skipW,
                              const float* __restrict__ c1W, const float* __restrict__ c2W,
                              const float* __restrict__ c3W, const float* __restrict__ W1,
                              const float* __restrict__ cw, unsigned short* __restrict__ wr) {
  int o = blockIdx.x * 256 + threadIdx.x;
  if (o < 8192) {  // proj: K=64, NT=8
    int off = o;
    int j = off & 7, t = off >> 3;
    int q = t & 3; t >>= 2;
    int c = t & 15; t >>= 4;
    int kb = t & 1, ct = t >> 1;
    int k = kb * 32 + q * 8 + j, col = ct * 16 + c;
    wr[o] = f2bf(projW[(size_t)k * 128 + col]);
  } else if (o < 73728) {  // skip/c1/c2/c3: K=128, NT=8
    int region = (o - 8192) >> 14;
    int off = (o - 8192) & 16383;
    const float* W = region == 0 ? skipW : region == 1 ? c1W : region == 2 ? c2W : c3W;
    int j = off & 7, t = off >> 3;
    int q = t & 3; t >>= 2;
    int c = t & 15; t >>= 4;
    int kb = t & 3, ct = t >> 2;
    int k = kb * 32 + q * 8 + j, col = ct * 16 + c;
    wr[o] = f2bf(W[(size_t)k * 128 + col]);
  } else if (o < 83968) {  // cls: K=128, NT=5 (cols 0..63 W1, 64 confW, 65..79 zero)
    int off = o - 73728;
    int j = off & 7, t = off >> 3;
    int q = t & 3; t >>= 2;
    int c = t & 15; t >>= 4;
    int kb = t & 3, ct = t >> 2;
    int k = kb * 32 + q * 8 + j, col = ct * 16 + c;
    float v = 0.f;
    if (col < 64) v = W1[(size_t)k * 64 + col];
    else if (col == 64) v = cw[k];
    wr[o] = f2bf(v);
  }
}

// ============================ MFMA GEMM ============================
template <int K, int NT, int ABF, int BN, int BIAS, int RELU, int OUTM, int SCH>
__global__ __launch_bounds__(256) void k_mgemm(
    const void* __restrict__ Ain, const unsigned short* __restrict__ Bw,
    const float* __restrict__ bias,
    const float* __restrict__ bnsums, const float* __restrict__ bng,
    const float* __restrict__ bnb,
    const unsigned short* __restrict__ skip,
    const float* __restrict__ a_s, const float* __restrict__ a_d,
    const float* __restrict__ confb,
    void* __restrict__ Cout, float* __restrict__ conf,
    float* __restrict__ scs, float* __restrict__ scd) {
  constexpr int KB = K / 32;
  __shared__ __align__(16) unsigned short sm[(8 + NT) * KB * 512];
  __shared__ float bnsc[128], bnsh[128];
  const int tid = threadIdx.x;
  const int r0 = blockIdx.x * 128;

  if constexpr (BN) {
    if (tid < K) {
      float invM = 1.f / (float)NN;
      float mu = bnsums[tid] * invM;
      float var = bnsums[K + tid] * invM - mu * mu;
      float sc = bng[tid] * rsqrtf(var + 1e-5f);
      bnsc[tid] = sc;
      bnsh[tid] = bnb[tid] - mu * sc;
    }
    __syncthreads();
  }

  // ---- stage A ----
  if constexpr (ABF) {
    const unsigned short* A = (const unsigned short*)Ain;
    constexpr int IT = 128 * (K / 8) / 256;
#pragma unroll
    for (int it = 0; it < IT; ++it) {
      int idx = it * 256 + tid;
      int r = idx / (K / 8);
      int k = (idx % (K / 8)) * 8;
      int gr = r0 + r;
      union { uint4 u4; unsigned short us[8]; } v;
      v.u4 = make_uint4(0, 0, 0, 0);
      if (gr < NN) v.u4 = *(const uint4*)(A + (size_t)gr * K + k);
      if constexpr (BN) {
        union { uint4 u4; unsigned short us[8]; } sv;
        if (BN == 3) {
          sv.u4 = make_uint4(0, 0, 0, 0);
          if (gr < NN) sv.u4 = *(const uint4*)(skip + (size_t)gr * 128 + k);
        }
#pragma unroll
        for (int j = 0; j < 8; ++j) {
          float f = bf2f(v.us[j]) * bnsc[k + j] + bnsh[k + j];
          if (BN == 3) f += bf2f(sv.us[j]);
          if (BN >= 2) f = fmaxf(f, 0.f);
          v.us[j] = f2bf(f);
        }
      }
      *(uint4*)&sm[((r >> 4) * KB + (k >> 5)) * 512 + (r & 15) * 32 + (k & 31)] = v.u4;
    }
  } else {
    const float* A = (const float*)Ain;
    constexpr int IT = 128 * (K / 4) / 256;
#pragma unroll
    for (int it = 0; it < IT; ++it) {
      int idx = it * 256 + tid;
      int r = idx / (K / 4);
      int k = (idx % (K / 4)) * 4;
      int gr = r0 + r;
      float4 av = make_float4(0.f, 0.f, 0.f, 0.f);
      if (gr < NN) av = *(const float4*)(A + (size_t)gr * K + k);
      if constexpr (BN) {
        av.x = av.x * bnsc[k + 0] + bnsh[k + 0];
        av.y = av.y * bnsc[k + 1] + bnsh[k + 1];
        av.z = av.z * bnsc[k + 2] + bnsh[k + 2];
        av.w = av.w * bnsc[k + 3] + bnsh[k + 3];
        if (BN >= 2) {
          av.x = fmaxf(av.x, 0.f); av.y = fmaxf(av.y, 0.f);
          av.z = fmaxf(av.z, 0.f); av.w = fmaxf(av.w, 0.f);
        }
      }
      ushort4 o;
      o.x = f2bf(av.x); o.y = f2bf(av.y); o.z = f2bf(av.z); o.w = f2bf(av.w);
      *(ushort4*)&sm[((r >> 4) * KB + (k >> 5)) * 512 + (r & 15) * 32 + (k & 31)] = o;
    }
  }
  // ---- stage B ----
  {
    constexpr int BW = NT * KB * 512;
#pragma unroll
    for (int it = 0; it < BW / 2048; ++it) {
      int idx = it * 256 + tid;
      *(uint4*)&sm[8 * KB * 512 + idx * 8] = *(const uint4*)(Bw + idx * 8);
    }
  }
  __syncthreads();

  // ---- MFMA ----
  const int lane = tid & 63, wv = tid >> 6;
  const int lr = lane & 15, lg = lane >> 4;
  const int fidx = lr * 32 + lg * 8;
  f32x4 acc[2][NT];
#pragma unroll
  for (int f = 0; f < 2; ++f)
#pragma unroll
    for (int ct = 0; ct < NT; ++ct) acc[f][ct] = (f32x4){0.f, 0.f, 0.f, 0.f};
#pragma unroll
  for (int kb = 0; kb < KB; ++kb) {
    short8 a0 = *(const short8*)&sm[((wv * 2 + 0) * KB + kb) * 512 + fidx];
    short8 a1 = *(const short8*)&sm[((wv * 2 + 1) * KB + kb) * 512 + fidx];
#pragma unroll
    for (int ct = 0; ct < NT; ++ct) {
      short8 b = *(const short8*)&sm[((8 + ct) * KB + kb) * 512 + fidx];
      acc[0][ct] = __builtin_amdgcn_mfma_f32_16x16x32_bf16(a0, b, acc[0][ct], 0, 0, 0);
      acc[1][ct] = __builtin_amdgcn_mfma_f32_16x16x32_bf16(a1, b, acc[1][ct], 0, 0, 0);
    }
  }

  // ---- fused attention scores ----
  if constexpr (SCH > 0) {
    constexpr int NH = (SCH == 1) ? 1 : 4;
    float asv[NT], adv[NT];
#pragma unroll
    for (int ct = 0; ct < NT; ++ct) {
      asv[ct] = a_s[ct * 16 + lr];
      adv[ct] = a_d[ct * 16 + lr];
    }
    float ps[2][4][NH], pd[2][4][NH];
#pragma unroll
    for (int f = 0; f < 2; ++f)
#pragma unroll
      for (int r = 0; r < 4; ++r)
#pragma unroll
        for (int h = 0; h < NH; ++h) { ps[f][r][h] = 0.f; pd[f][r][h] = 0.f; }
#pragma unroll
    for (int f = 0; f < 2; ++f)
#pragma unroll
      for (int ct = 0; ct < NT; ++ct) {
        int h = (NH == 1) ? 0 : (ct >> 1);
#pragma unroll
        for (int r = 0; r < 4; ++r) {
          ps[f][r][h] = fmaf(acc[f][ct][r], asv[ct], ps[f][r][h]);
          pd[f][r][h] = fmaf(acc[f][ct][r], adv[ct], pd[f][r][h]);
        }
      }
#pragma unroll
    for (int off = 1; off < 16; off <<= 1)
#pragma unroll
      for (int f = 0; f < 2; ++f)
#pragma unroll
        for (int r = 0; r < 4; ++r)
#pragma unroll
          for (int h = 0; h < NH; ++h) {
            ps[f][r][h] += __shfl_xor(ps[f][r][h], off);
            pd[f][r][h] += __shfl_xor(pd[f][r][h], off);
          }
    if (lr == 0) {
#pragma unroll
      for (int f = 0; f < 2; ++f) {
        int rowb = r0 + (wv * 2 + f) * 16 + lg * 4;
#pragma unroll
        for (int r = 0; r < 4; ++r) {
          int gr = rowb + r;
          if (gr < NN) {
            if (NH == 4) {
              float4 vs = make_float4(ps[f][r][0], ps[f][r][1], ps[f][r][2], ps[f][r][3]);
              float4 vd = make_float4(pd[f][r][0], pd[f][r][1], pd[f][r][2], pd[f][r][3]);
              *(float4*)(scs + (size_t)gr * 4) = vs;
              *(float4*)(scd + (size_t)gr * 4) = vd;
            } else {
              scs[gr] = ps[f][r][0];
              scd[gr] = pd[f][r][0];
            }
          }
        }
      }
    }
  }

  // ---- epilogue ----
#pragma unroll
  for (int f = 0; f < 2; ++f) {
    int rowb = r0 + (wv * 2 + f) * 16 + lg * 4;
#pragma unroll
    for (int ct = 0; ct < NT; ++ct) {
      int col = ct * 16 + lr;
      if constexpr (OUTM == 2) {
        if (col < 64) {
          float bb = bias[col];
#pragma unroll
          for (int r = 0; r < 4; ++r) {
            int gr = rowb + r;
            if (gr < NN)
              ((unsigned short*)Cout)[(size_t)gr * 64 + col] =
                  f2bf(fmaxf(acc[f][ct][r] + bb, 0.f));
          }
        } else if (col == 64) {
          float cb = confb[0];
#pragma unroll
          for (int r = 0; r < 4; ++r) {
            int gr = rowb + r;
            if (gr < NN) conf[gr] = 1.f / (1.f + __expf(-(acc[f][ct][r] + cb)));
          }
        }
      } else {
        float bb = BIAS ? bias[col] : 0.f;
#pragma unroll
        for (int r = 0; r < 4; ++r) {
          int gr = rowb + r;
          if (gr < NN) {
            float o = acc[f][ct][r] + bb;
            if (RELU) o = fmaxf(o, 0.f);
            ((unsigned short*)Cout)[(size_t)gr * 128 + col] = f2bf(o);
          }
        }
      }
    }
  }
}

// ============================ GAT aggregation ============================
// One wave per dst node, 8 edges in flight: 8 lanes x 16 bf16 channels per edge.
template <int H>
__global__ __launch_bounds__(256) void k_agg(const unsigned short* __restrict__ hp,
                                             const float* __restrict__ scs,
                                             const float* __restrict__ scd,
                                             const int* __restrict__ rowp,
                                             const int* __restrict__ srcl,
                                             const float* __restrict__ bias,
                                             unsigned short* __restrict__ out) {
  int lane = threadIdx.x & 63;
  int n = (blockIdx.x * 256 + threadIdx.x) >> 6;
  if (n >= NN) return;
  int g = lane >> 3;    // edge group 0..7
  int l8 = lane & 7;    // channel lane within edge
  int c0 = l8 * 16;
  int hid = (H == 1) ? 0 : (l8 >> 1);
  float sd = scd[(size_t)n * H + hid];
  int beg = rowp[n], end = rowp[n + 1];
  float a[16];
#pragma unroll
  for (int i = 0; i < 16; ++i) a[i] = 0.f;
  float sw = 0.f;
  int k = beg + g;
  int s_next = (k < end) ? srcl[k] : 0;
  for (; k < end; k += 8) {
    int s = s_next;
    int kn = k + 8;
    if (kn < end) s_next = srcl[kn];
    float e = scs[(size_t)s * H + hid] + sd;
    e = fmaxf(e, 0.f) + 0.2f * fminf(e, 0.f);  // leaky relu
    float w = __expf(e);
    const uint4* row = (const uint4*)(hp + (size_t)s * 128 + c0);
    uint4 u0 = row[0];
    uint4 u1 = row[1];
    a[0] = fmaf(w, bf2f_lo(u0.x), a[0]);
    a[1] = fmaf(w, bf2f_hi(u0.x), a[1]);
    a[2] = fmaf(w, bf2f_lo(u0.y), a[2]);
    a[3] = fmaf(w, bf2f_hi(u0.y), a[3]);
    a[4] = fmaf(w, bf2f_lo(u0.z), a[4]);
    a[5] = fmaf(w, bf2f_hi(u0.z), a[5]);
    a[6] = fmaf(w, bf2f_lo(u0.w), a[6]);
    a[7] = fmaf(w, bf2f_hi(u0.w), a[7]);
    a[8]  = fmaf(w, bf2f_lo(u1.x), a[8]);
    a[9]  = fmaf(w, bf2f_hi(u1.x), a[9]);
    a[10] = fmaf(w, bf2f_lo(u1.y), a[10]);
    a[11] = fmaf(w, bf2f_hi(u1.y), a[11]);
    a[12] = fmaf(w, bf2f_lo(u1.z), a[12]);
    a[13] = fmaf(w, bf2f_hi(u1.z), a[13]);
    a[14] = fmaf(w, bf2f_lo(u1.w), a[14]);
    a[15] = fmaf(w, bf2f_hi(u1.w), a[15]);
    sw += w;
  }
#pragma unroll
  for (int i = 0; i < 16; ++i) {
    a[i] += __shfl_xor(a[i], 8);
    a[i] += __shfl_xor(a[i], 16);
    a[i] += __shfl_xor(a[i], 32);
  }
  sw += __shfl_xor(sw, 8);
  sw += __shfl_xor(sw, 16);
  sw += __shfl_xor(sw, 32);
  if (g == 0) {
    float inv = 1.f / (sw + 1e-16f);
    unsigned wb[8];
#pragma unroll
    for (int j = 0; j < 8; ++j) {
      float o0 = a[2 * j] * inv + bias[c0 + 2 * j];
      float o1 = a[2 * j + 1] * inv + bias[c0 + 2 * j + 1];
      wb[j] = (unsigned)f2bf(o0) | ((unsigned)f2bf(o1) << 16);
    }
    uint4 q0 = make_uint4(wb[0], wb[1], wb[2], wb[3]);
    uint4 q1 = make_uint4(wb[4], wb[5], wb[6], wb[7]);
    *(uint4*)(out + (size_t)n * 128 + c0) = q0;
    *(uint4*)(out + (size_t)n * 128 + c0 + 8) = q1;
  }
}

// ============================ classifier tail ============================
__global__ __launch_bounds__(256) void k_head2(const unsigned short* __restrict__ C1,
                                               const float* __restrict__ W2,
                                               const float* __restrict__ b2,
                                               const float* __restrict__ W3,
                                               const float* __restrict__ b3,
                                               float* __restrict__ logits) {
  __shared__ float W2s[64 * 32];
  __shared__ float c2s[32 * 32];
  __shared__ unsigned short c1s[32 * 64];
  __shared__ float b2s[32], W3s[64], b3s[2];
  int tid = threadIdx.x;
  for (int i = tid; i < 64 * 32; i += 256) W2s[i] = W2[i];
  if (tid < 64) W3s[tid] = W3[tid];
  if (tid < 32) b2s[tid] = b2[tid];
  if (tid < 2) b3s[tid] = b3[tid];
  int n0 = blockIdx.x * 32;
  {
    size_t base = (size_t)n0 * 64;
    *(uint4*)&c1s[tid * 8] = *(const uint4*)(C1 + base + (size_t)tid * 8);
  }
  __syncthreads();
  int j = tid & 31;
  int g8 = tid >> 5;
#pragma unroll
  for (int g = 0; g < 4; ++g) {
    int node = g * 8 + g8;
    float acc = b2s[j];
#pragma unroll 8
    for (int k = 0; k < 64; ++k) acc = fmaf(bf2f(c1s[node * 64 + k]), W2s[k * 32 + j], acc);
    c2s[node * 32 + j] = fmaxf(acc, 0.f);
  }
  __syncthreads();
  if (tid < 64) {
    int node = tid >> 1, jj = tid & 1;
    float acc = b3s[jj];
#pragma unroll 8
    for (int k = 0; k < 32; ++k) acc = fmaf(c2s[node * 32 + k], W3s[k * 2 + jj], acc);
    int n = n0 + node;
    if (n < NN) logits[(size_t)n * 2 + jj] = acc;
  }
}

// ============================ launch ============================
extern "C" void kernel_launch(void* const* d_in, const int* in_sizes, int n_in,
                              void* d_out, int out_size, void* d_ws, size_t ws_size,
                              hipStream_t stream) {
  (void)in_sizes; (void)n_in; (void)out_size; (void)ws_size;
  const float* x       = (const float*)d_in[0];
  const int*   ei      = (const int*)d_in[1];
  const float* in_g    = (const float*)d_in[2];
  const float* in_b    = (const float*)d_in[3];
  const float* projW   = (const float*)d_in[4];
  const float* projb   = (const float*)d_in[5];
  const float* skipW   = (const float*)d_in[6];
  const float* skipb   = (const float*)d_in[7];
  const float* c1W     = (const float*)d_in[8];
  const float* c1as    = (const float*)d_in[9];
  const float* c1ad    = (const float*)d_in[10];
  const float* c1b     = (const float*)d_in[11];
  const float* bn1g    = (const float*)d_in[12];
  const float* bn1b    = (const float*)d_in[13];
  const float* c2W     = (const float*)d_in[14];
  const float* c2as    = (const float*)d_in[15];
  const float* c2ad    = (const float*)d_in[16];
  const float* c2b     = (const float*)d_in[17];
  const float* bn2g    = (const float*)d_in[18];
  const float* bn2b    = (const float*)d_in[19];
  const float* c3W     = (const float*)d_in[20];
  const float* c3as    = (const float*)d_in[21];
  const float* c3ad    = (const float*)d_in[22];
  const float* c3b     = (const float*)d_in[23];
  const float* bn3g    = (const float*)d_in[24];
  const float* bn3b    = (const float*)d_in[25];
  const float* clsW1   = (const float*)d_in[26];
  const float* clsb1   = (const float*)d_in[27];
  const float* clsW2   = (const float*)d_in[28];
  const float* clsb2   = (const float*)d_in[29];
  const float* clsW3   = (const float*)d_in[30];
  const float* clsb3   = (const float*)d_in[31];
  const float* confW   = (const float*)d_in[32];
  const float* confb   = (const float*)d_in[33];

  float* out_logits = (float*)d_out;
  float* out_conf   = (float*)d_out + (size_t)NN * 2;

  char* p = (char*)d_ws;
  auto alloc = [&](size_t bytes) -> char* {
    char* r = p;
    p += (bytes + 255) & ~(size_t)255;
    return r;
  };
  unsigned short* hr  = (unsigned short*)alloc((size_t)NN * 128 * 2);  // relu(proj)
  unsigned short* hsk = (unsigned short*)alloc((size_t)NN * 128 * 2);  // h_skip
  unsigned short* hb  = (unsigned short*)alloc((size_t)NN * 128 * 2);  // conv h / C1
  unsigned short* agA = (unsigned short*)alloc((size_t)NN * 128 * 2);  // agg out (L1, L3)
  unsigned short* agB = (unsigned short*)alloc((size_t)NN * 128 * 2);  // agg out (L2)
  float* scs   = (float*)alloc((size_t)NN * 4 * 4);
  float* scd   = (float*)alloc((size_t)NN * 4 * 4);
  float* stats = (float*)alloc(4 * 256 * 4);
  int*   rowp  = (int*)alloc((size_t)(NN + 1) * 4);
  int*   gpos  = (int*)alloc((size_t)NBK * 4);
  int*   ebase = (int*)alloc((size_t)NBK * 4);
  unsigned* binned = (unsigned*)alloc((size_t)NBK * BCAP * 4);
  int*   srcl  = (int*)alloc((size_t)TOT_E * 4);
  unsigned short* wr = (unsigned short*)alloc(83968 * 2);
  unsigned short* wr_proj = wr;
  unsigned short* wr_skip = wr + 8192;
  unsigned short* wr_c1   = wr + 24576;
  unsigned short* wr_c2   = wr + 40960;
  unsigned short* wr_c3   = wr + 57344;
  unsigned short* wr_cls  = wr + 73728;
  unsigned short* C1 = hb;  // reuse after L3 agg

  const int GB = (NN + 127) / 128;
  const int WB = (NN + 3) / 4;
  const int CB = (NN + 31) / 32;

  k_reorder_all<<<328, 256, 0, stream>>>(projW, skipW, c1W, c2W, c3W, clsW1, confW, wr);
  hipMemsetAsync(gpos, 0, (size_t)NBK * 4, stream);
  hipMemsetAsync(stats, 0, 4 * 256 * 4, stream);

  // ---- CSR build (bucket binning) ----
  k_bin<<<256, 512, 0, stream>>>(ei, gpos, binned);
  k_bscan<<<1, 512, 0, stream>>>(gpos, ebase, rowp);
  k_bucket<<<NBK, 256, 0, stream>>>(binned, gpos, ebase, rowp, srcl);

  // ---- input BN stats ----
  k_bn_stats<64><<<256, 256, 0, stream>>>(x, stats);

  // ---- proj: hr = relu(bn(x) @ projW + b) ----
  k_mgemm<64, 8, 0, 1, 1, 1, 1, 0><<<GB, 256, 0, stream>>>(
      x, wr_proj, projb, stats, in_g, in_b, nullptr, nullptr, nullptr, nullptr,
      hr, nullptr, nullptr, nullptr);
  // ---- skip: hsk = hr @ skipW + b ----
  k_mgemm<128, 8, 1, 0, 1, 0, 1, 0><<<GB, 256, 0, stream>>>(
      hr, wr_skip, skipb, nullptr, nullptr, nullptr, nullptr, nullptr, nullptr, nullptr,
      hsk, nullptr, nullptr, nullptr);

  // ---- GAT layer 1 ----
  k_mgemm<128, 8, 1, 0, 0, 0, 1, 4><<<GB, 256, 0, stream>>>(
      hr, wr_c1, nullptr, nullptr, nullptr, nullptr, nullptr, c1as, c1ad, nullptr,
      hb, nullptr, scs, scd);
  k_agg<4><<<WB, 256, 0, stream>>>(hb, scs, scd, rowp, srcl, c1b, agA);
  k_bn_stats_bf<<<256, 256, 0, stream>>>(agA, stats + 256);

  // ---- GAT layer 2 (bn1+relu fused into A staging) ----
  k_mgemm<128, 8, 1, 2, 0, 0, 1, 4><<<GB, 256, 0, stream>>>(
      agA, wr_c2, nullptr, stats + 256, bn1g, bn1b, nullptr, c2as, c2ad, nullptr,
      hb, nullptr, scs, scd);
  k_agg<4><<<WB, 256, 0, stream>>>(hb, scs, scd, rowp, srcl, c2b, agB);
  k_bn_stats_bf<<<256, 256, 0, stream>>>(agB, stats + 512);

  // ---- GAT layer 3 (H=1; bn2+relu fused) ----
  k_mgemm<128, 8, 1, 2, 0, 0, 1, 1><<<GB, 256, 0, stream>>>(
      agB, wr_c3, nullptr, stats + 512, bn2g, bn2b, nullptr, c3as, c3ad, nullptr,
      hb, nullptr, scs, scd);
  k_agg<1><<<WB, 256, 0, stream>>>(hb, scs, scd, rowp, srcl, c3b, agA);
  k_bn_stats_bf<<<256, 256, 0, stream>>>(agA, stats + 768);

  // ---- classifier stage 1: relu(bn3(agA)+hsk) @ [W1|confW] ----
  k_mgemm<128, 5, 1, 3, 1, 0, 2, 0><<<GB, 256, 0, stream>>>(
      agA, wr_cls, clsb1, stats + 768, bn3g, bn3b, hsk, nullptr, nullptr, confb,
      C1, out_conf, nullptr, nullptr);
  // ---- classifier tail ----
  k_head2<<<CB, 256, 0, stream>>>(C1, clsW2, clsb2, clsW3, clsb3, out_logits);
}

// Round 6
// 280.157 us; speedup vs baseline: 2.9438x; 1.1781x over previous
//
#include <hip/hip_runtime.h>
#include <cstdint>
#include <cstddef>

#define NN 50000
#define EE 800000
#define TOT_E (NN + EE)
#define NBK 391      // buckets of 128 dst nodes
#define BCAP 2560    // bucket capacity (mean 2048 -> 11 sigma headroom)

typedef __attribute__((ext_vector_type(8))) short short8;
typedef __attribute__((ext_vector_type(4))) float f32x4;

static __device__ __forceinline__ unsigned short f2bf(float f) {
  union { float f; unsigned u; } v;
  v.f = f;
  unsigned r = v.u + 0x7FFFu + ((v.u >> 16) & 1u);  // RNE
  return (unsigned short)(r >> 16);
}
static __device__ __forceinline__ float bf2f(unsigned short u) {
  union { unsigned u; float f; } v;
  v.u = ((unsigned)u) << 16;
  return v.f;
}
static __device__ __forceinline__ float bf2f_lo(unsigned u) {
  union { unsigned u; float f; } v;
  v.u = u << 16;
  return v.f;
}
static __device__ __forceinline__ float bf2f_hi(unsigned u) {
  union { unsigned u; float f; } v;
  v.u = u & 0xFFFF0000u;
  return v.f;
}

// ============================ CSR build: bucket binning ============================
__global__ __launch_bounds__(512) void k_bin(const int* __restrict__ ei,
                                             int* __restrict__ gpos,
                                             unsigned* __restrict__ binned) {
  __shared__ int cnt[512];
  __shared__ int base[512];
  int tx = threadIdx.x;
  cnt[tx] = 0;
  __syncthreads();
  int e0 = blockIdx.x * 3125;
  int e1 = e0 + 3125;
  if (e1 > EE) e1 = EE;
  for (int i = e0 + tx; i < e1; i += 512) {
    int d = ei[EE + i];
    atomicAdd(&cnt[d >> 7], 1);
  }
  __syncthreads();
  if (tx < NBK) {
    int c = cnt[tx];
    base[tx] = c ? atomicAdd(&gpos[tx], c) : 0;
    cnt[tx] = 0;
  }
  __syncthreads();
  for (int i = e0 + tx; i < e1; i += 512) {
    int s = ei[i];
    int d = ei[EE + i];
    int b = d >> 7;
    int slot = base[b] + atomicAdd(&cnt[b], 1);
    if (slot < BCAP) binned[(size_t)b * BCAP + slot] = (unsigned)s | ((unsigned)(d & 127) << 16);
  }
}
__global__ __launch_bounds__(512) void k_bscan(const int* __restrict__ gpos,
                                               int* __restrict__ ebase,
                                               int* __restrict__ rowp) {
  __shared__ int sh[512];
  int tx = threadIdx.x;
  int v = 0;
  if (tx < NBK) {
    int nodes = NN - (tx << 7);
    if (nodes > 128) nodes = 128;
    int g = gpos[tx];
    if (g > BCAP) g = BCAP;
    v = g + nodes;
  }
  sh[tx] = v;
  __syncthreads();
  for (int off = 1; off < 512; off <<= 1) {
    int t = (tx >= off) ? sh[tx - off] : 0;
    __syncthreads();
    sh[tx] += t;
    __syncthreads();
  }
  if (tx < NBK) ebase[tx] = sh[tx] - v;
  if (tx == NBK - 1) rowp[NN] = sh[tx];
}
__global__ __launch_bounds__(256) void k_bucket(const unsigned* __restrict__ binned,
                                                const int* __restrict__ gpos,
                                                const int* __restrict__ ebase,
                                                int* __restrict__ rowp,
                                                int* __restrict__ srcl) {
  __shared__ int cnt[128], offs[128], cur[128];
  int b = blockIdx.x, tid = threadIdx.x;
  int n0 = b << 7;
  int nodes = NN - n0;
  if (nodes > 128) nodes = 128;
  int ne = gpos[b];
  if (ne > BCAP) ne = BCAP;
  int eb = ebase[b];
  if (tid < 128) cnt[tid] = (tid < nodes) ? 1 : 0;  // 1 = self-loop
  __syncthreads();
  const unsigned* bb = binned + (size_t)b * BCAP;
  for (int i = tid; i < ne; i += 256) atomicAdd(&cnt[bb[i] >> 16], 1);
  __syncthreads();
  if (tid < 128) offs[tid] = cnt[tid];
  __syncthreads();
  for (int o = 1; o < 128; o <<= 1) {
    int t = (tid < 128 && tid >= o) ? offs[tid - o] : 0;
    __syncthreads();
    if (tid < 128) offs[tid] += t;
    __syncthreads();
  }
  if (tid < 128 && tid < nodes) {
    int ex = offs[tid] - cnt[tid];
    rowp[n0 + tid] = eb + ex;
    srcl[eb + ex] = n0 + tid;  // self-loop first (segment order irrelevant)
    cur[tid] = ex + 1;
  }
  __syncthreads();
  for (int i = tid; i < ne; i += 256) {
    unsigned e = bb[i];
    int r = atomicAdd(&cur[e >> 16], 1);
    srcl[eb + r] = (int)(e & 0xFFFFu);
  }
}

// ============================ BN stats for x (f32, C=64) ============================
__global__ __launch_bounds__(256) void k_bn_stats64(const float* __restrict__ x,
                                                    float* __restrict__ sums) {
  int col = threadIdx.x & 63;
  int rsub = threadIdx.x >> 6;
  float s = 0.f, q = 0.f;
  for (int r = blockIdx.x * 4 + rsub; r < NN; r += gridDim.x * 4) {
    float v = x[(size_t)r * 64 + col];
    s += v;
    q += v * v;
  }
  __shared__ float bs[256], bq[256];
  bs[threadIdx.x] = s;
  bq[threadIdx.x] = q;
  __syncthreads();
  if (threadIdx.x < 64) {
#pragma unroll
    for (int i = 1; i < 4; ++i) {
      s += bs[threadIdx.x + i * 64];
      q += bq[threadIdx.x + i * 64];
    }
    atomicAdd(&sums[col], s);
    atomicAdd(&sums[64 + col], q);
  }
}

// ============================ fused weight reorder ============================
__global__ void k_reorder_all(const float* __restrict__ projW, const float* __restrict__ skipW,
                              const float* __restrict__ c1W, const float* __restrict__ c2W,
                              const float* __restrict__ c3W, const float* __restrict__ W1,
                              const float* __restrict__ cw, unsigned short* __restrict__ wr) {
  int o = blockIdx.x * 256 + threadIdx.x;
  if (o < 8192) {  // proj: K=64, NT=8
    int off = o;
    int j = off & 7, t = off >> 3;
    int q = t & 3; t >>= 2;
    int c = t & 15; t >>= 4;
    int kb = t & 1, ct = t >> 1;
    int k = kb * 32 + q * 8 + j, col = ct * 16 + c;
    wr[o] = f2bf(projW[(size_t)k * 128 + col]);
  } else if (o < 73728) {  // skip/c1/c2/c3: K=128, NT=8
    int region = (o - 8192) >> 14;
    int off = (o - 8192) & 16383;
    const float* W = region == 0 ? skipW : region == 1 ? c1W : region == 2 ? c2W : c3W;
    int j = off & 7, t = off >> 3;
    int q = t & 3; t >>= 2;
    int c = t & 15; t >>= 4;
    int kb = t & 3, ct = t >> 2;
    int k = kb * 32 + q * 8 + j, col = ct * 16 + c;
    wr[o] = f2bf(W[(size_t)k * 128 + col]);
  } else if (o < 83968) {  // cls: K=128, NT=5 (cols 0..63 W1, 64 confW, rest 0)
    int off = o - 73728;
    int j = off & 7, t = off >> 3;
    int q = t & 3; t >>= 2;
    int c = t & 15; t >>= 4;
    int kb = t & 3, ct = t >> 2;
    int k = kb * 32 + q * 8 + j, col = ct * 16 + c;
    float v = 0.f;
    if (col < 64) v = W1[(size_t)k * 64 + col];
    else if (col == 64) v = cw[k];
    wr[o] = f2bf(v);
  }
}

// ============================ shared device helpers ============================
template <int NT, int NH>
static __device__ __forceinline__ void write_scores(const f32x4 (&acc)[2][NT],
                                                    const float* __restrict__ a_s,
                                                    const float* __restrict__ a_d,
                                                    int r0, int lane, int wv,
                                                    float* __restrict__ scs,
                                                    float* __restrict__ scd) {
  const int lr = lane & 15, lg = lane >> 4;
  float asv[NT], adv[NT];
#pragma unroll
  for (int ct = 0; ct < NT; ++ct) {
    asv[ct] = a_s[ct * 16 + lr];
    adv[ct] = a_d[ct * 16 + lr];
  }
  float ps[2][4][NH], pd[2][4][NH];
#pragma unroll
  for (int f = 0; f < 2; ++f)
#pragma unroll
    for (int r = 0; r < 4; ++r)
#pragma unroll
      for (int h = 0; h < NH; ++h) { ps[f][r][h] = 0.f; pd[f][r][h] = 0.f; }
#pragma unroll
  for (int f = 0; f < 2; ++f)
#pragma unroll
    for (int ct = 0; ct < NT; ++ct) {
      int h = (NH == 1) ? 0 : (ct >> 1);
#pragma unroll
      for (int r = 0; r < 4; ++r) {
        ps[f][r][h] = fmaf(acc[f][ct][r], asv[ct], ps[f][r][h]);
        pd[f][r][h] = fmaf(acc[f][ct][r], adv[ct], pd[f][r][h]);
      }
    }
#pragma unroll
  for (int off = 1; off < 16; off <<= 1)
#pragma unroll
    for (int f = 0; f < 2; ++f)
#pragma unroll
      for (int r = 0; r < 4; ++r)
#pragma unroll
        for (int h = 0; h < NH; ++h) {
          ps[f][r][h] += __shfl_xor(ps[f][r][h], off);
          pd[f][r][h] += __shfl_xor(pd[f][r][h], off);
        }
  if (lr == 0) {
#pragma unroll
    for (int f = 0; f < 2; ++f) {
      int rowb = r0 + (wv * 2 + f) * 16 + lg * 4;
#pragma unroll
      for (int r = 0; r < 4; ++r) {
        int gr = rowb + r;
        if (gr < NN) {
          if (NH == 4) {
            float4 vs = make_float4(ps[f][r][0], ps[f][r][1], ps[f][r][2], ps[f][r][3]);
            float4 vd = make_float4(pd[f][r][0], pd[f][r][1], pd[f][r][2], pd[f][r][3]);
            *(float4*)(scs + (size_t)gr * 4) = vs;
            *(float4*)(scd + (size_t)gr * 4) = vd;
          } else {
            scs[gr] = ps[f][r][0];
            scd[gr] = pd[f][r][0];
          }
        }
      }
    }
  }
}

template <int NT, int BIAS, int RELU>
static __device__ __forceinline__ void write_out_bf(const f32x4 (&acc)[2][NT],
                                                    const float* __restrict__ bias,
                                                    int r0, int lane, int wv,
                                                    unsigned short* __restrict__ out) {
  const int lr = lane & 15, lg = lane >> 4;
#pragma unroll
  for (int f = 0; f < 2; ++f) {
    int rowb = r0 + (wv * 2 + f) * 16 + lg * 4;
#pragma unroll
    for (int ct = 0; ct < NT; ++ct) {
      int col = ct * 16 + lr;
      float bb = BIAS ? bias[col] : 0.f;
#pragma unroll
      for (int r = 0; r < 4; ++r) {
        int gr = rowb + r;
        if (gr < NN) {
          float o = acc[f][ct][r] + bb;
          if (RELU) o = fmaxf(o, 0.f);
          out[(size_t)gr * 128 + col] = f2bf(o);
        }
      }
    }
  }
}

// ============================ MFMA GEMM ============================
// BN: 0 none, 1 sc/sh, 2 +relu, 3 +skip+relu. BNP: 0 = single sums buffer, 1 = 64 partials.
// OUTM: 1 bf16 out stride 128; 2 classifier (C1 -> LDS, c2+logits+conf in-kernel).
// SCH: 0 off, 1/4 GAT scores in epilogue.
template <int K, int NT, int ABF, int BN, int BNP, int BIAS, int RELU, int OUTM, int SCH>
__global__ __launch_bounds__(256) void k_mgemm(
    const void* __restrict__ Ain, const unsigned short* __restrict__ Bw,
    const float* __restrict__ bias,
    const float* __restrict__ bnsums, const float* __restrict__ bng,
    const float* __restrict__ bnb,
    const unsigned short* __restrict__ skip,
    const float* __restrict__ a_s, const float* __restrict__ a_d,
    const float* __restrict__ confb,
    void* __restrict__ Cout, float* __restrict__ conf,
    float* __restrict__ scs, float* __restrict__ scd,
    const float* __restrict__ W2, const float* __restrict__ b2,
    const float* __restrict__ W3, const float* __restrict__ b3,
    float* __restrict__ logits) {
  constexpr int KB = K / 32;
  __shared__ __align__(16) unsigned short sm[(8 + NT) * KB * 512];
  __shared__ float bnsc[128], bnsh[128];
  const int tid = threadIdx.x;
  const int r0 = blockIdx.x * 128;

  if constexpr (BN) {
    if (tid < K) {
      float s, q;
      if constexpr (BNP) {
        s = 0.f; q = 0.f;
#pragma unroll 8
        for (int pp = 0; pp < 64; ++pp) {
          s += bnsums[pp * 256 + tid];
          q += bnsums[pp * 256 + 128 + tid];
        }
      } else {
        s = bnsums[tid];
        q = bnsums[K + tid];
      }
      float invM = 1.f / (float)NN;
      float mu = s * invM;
      float var = q * invM - mu * mu;
      float sc = bng[tid] * rsqrtf(var + 1e-5f);
      bnsc[tid] = sc;
      bnsh[tid] = bnb[tid] - mu * sc;
    }
    __syncthreads();
  }

  // ---- stage A ----
  if constexpr (ABF) {
    const unsigned short* A = (const unsigned short*)Ain;
    constexpr int IT = 128 * (K / 8) / 256;
#pragma unroll
    for (int it = 0; it < IT; ++it) {
      int idx = it * 256 + tid;
      int r = idx / (K / 8);
      int k = (idx % (K / 8)) * 8;
      int gr = r0 + r;
      union { uint4 u4; unsigned short us[8]; } v;
      v.u4 = make_uint4(0, 0, 0, 0);
      if (gr < NN) v.u4 = *(const uint4*)(A + (size_t)gr * K + k);
      if constexpr (BN) {
        union { uint4 u4; unsigned short us[8]; } sv;
        if (BN == 3) {
          sv.u4 = make_uint4(0, 0, 0, 0);
          if (gr < NN) sv.u4 = *(const uint4*)(skip + (size_t)gr * 128 + k);
        }
#pragma unroll
        for (int j = 0; j < 8; ++j) {
          float f = bf2f(v.us[j]) * bnsc[k + j] + bnsh[k + j];
          if (BN == 3) f += bf2f(sv.us[j]);
          if (BN >= 2) f = fmaxf(f, 0.f);
          v.us[j] = f2bf(f);
        }
      }
      *(uint4*)&sm[((r >> 4) * KB + (k >> 5)) * 512 + (r & 15) * 32 + (k & 31)] = v.u4;
    }
  } else {
    const float* A = (const float*)Ain;
    constexpr int IT = 128 * (K / 4) / 256;
#pragma unroll
    for (int it = 0; it < IT; ++it) {
      int idx = it * 256 + tid;
      int r = idx / (K / 4);
      int k = (idx % (K / 4)) * 4;
      int gr = r0 + r;
      float4 av = make_float4(0.f, 0.f, 0.f, 0.f);
      if (gr < NN) av = *(const float4*)(A + (size_t)gr * K + k);
      if constexpr (BN) {
        av.x = av.x * bnsc[k + 0] + bnsh[k + 0];
        av.y = av.y * bnsc[k + 1] + bnsh[k + 1];
        av.z = av.z * bnsc[k + 2] + bnsh[k + 2];
        av.w = av.w * bnsc[k + 3] + bnsh[k + 3];
        if (BN >= 2) {
          av.x = fmaxf(av.x, 0.f); av.y = fmaxf(av.y, 0.f);
          av.z = fmaxf(av.z, 0.f); av.w = fmaxf(av.w, 0.f);
        }
      }
      ushort4 o;
      o.x = f2bf(av.x); o.y = f2bf(av.y); o.z = f2bf(av.z); o.w = f2bf(av.w);
      *(ushort4*)&sm[((r >> 4) * KB + (k >> 5)) * 512 + (r & 15) * 32 + (k & 31)] = o;
    }
  }
  // ---- stage B ----
  {
    constexpr int BW = NT * KB * 512;
#pragma unroll
    for (int it = 0; it < BW / 2048; ++it) {
      int idx = it * 256 + tid;
      *(uint4*)&sm[8 * KB * 512 + idx * 8] = *(const uint4*)(Bw + idx * 8);
    }
  }
  __syncthreads();

  // ---- MFMA ----
  const int lane = tid & 63, wv = tid >> 6;
  const int lr = lane & 15, lg = lane >> 4;
  const int fidx = lr * 32 + lg * 8;
  f32x4 acc[2][NT];
#pragma unroll
  for (int f = 0; f < 2; ++f)
#pragma unroll
    for (int ct = 0; ct < NT; ++ct) acc[f][ct] = (f32x4){0.f, 0.f, 0.f, 0.f};
#pragma unroll
  for (int kb = 0; kb < KB; ++kb) {
    short8 a0 = *(const short8*)&sm[((wv * 2 + 0) * KB + kb) * 512 + fidx];
    short8 a1 = *(const short8*)&sm[((wv * 2 + 1) * KB + kb) * 512 + fidx];
#pragma unroll
    for (int ct = 0; ct < NT; ++ct) {
      short8 b = *(const short8*)&sm[((8 + ct) * KB + kb) * 512 + fidx];
      acc[0][ct] = __builtin_amdgcn_mfma_f32_16x16x32_bf16(a0, b, acc[0][ct], 0, 0, 0);
      acc[1][ct] = __builtin_amdgcn_mfma_f32_16x16x32_bf16(a1, b, acc[1][ct], 0, 0, 0);
    }
  }

  if constexpr (SCH > 0) {
    write_scores<NT, (SCH == 1) ? 1 : 4>(acc, a_s, a_d, r0, lane, wv, scs, scd);
  }

  if constexpr (OUTM == 2) {
    // -------- classifier tail in-kernel (reuse sm) --------
    __syncthreads();  // all MFMA reads of sm complete
    unsigned short* c1s = sm;                 // [128][65] bf16
    float* W2s = (float*)(sm + 8320);         // 64*32
    float* c2s = (float*)(sm + 12416);        // [128][33]
    float* W3s = (float*)(sm + 20864);        // 64
    float* b2s = (float*)(sm + 20992);        // 32
    float* b3s = (float*)(sm + 21056);        // 2
    for (int i = tid; i < 2048; i += 256) W2s[i] = W2[i];
    if (tid < 64) W3s[tid] = W3[tid];
    if (tid < 32) b2s[tid] = b2[tid];
    if (tid < 2) b3s[tid] = b3[tid];
#pragma unroll
    for (int f = 0; f < 2; ++f) {
      int lrow = (wv * 2 + f) * 16 + lg * 4;
#pragma unroll
      for (int ct = 0; ct < NT; ++ct) {
        int col = ct * 16 + lr;
        if (col < 64) {
          float bb = bias[col];
#pragma unroll
          for (int r = 0; r < 4; ++r)
            c1s[(lrow + r) * 65 + col] = f2bf(fmaxf(acc[f][ct][r] + bb, 0.f));
        } else if (col == 64) {
          float cb = confb[0];
#pragma unroll
          for (int r = 0; r < 4; ++r) {
            int gr = r0 + lrow + r;
            if (gr < NN) conf[gr] = 1.f / (1.f + __expf(-(acc[f][ct][r] + cb)));
          }
        }
      }
    }
    __syncthreads();
    // c2 = relu(C1 @ W2 + b2): 128 nodes x 32 cols; thread -> node=tid&127, 16 cols
    {
      int node = tid & 127;
      int cb = (tid >> 7) * 16;
      float a2[16];
#pragma unroll
      for (int i = 0; i < 16; ++i) a2[i] = b2s[cb + i];
      for (int k = 0; k < 64; ++k) {
        float v = bf2f(c1s[node * 65 + k]);
#pragma unroll
        for (int i = 0; i < 16; ++i) a2[i] = fmaf(v, W2s[k * 32 + cb + i], a2[i]);
      }
#pragma unroll
      for (int i = 0; i < 16; ++i) c2s[node * 33 + cb + i] = fmaxf(a2[i], 0.f);
    }
    __syncthreads();
    {
      int node = tid >> 1, j = tid & 1;
      float s3 = b3s[j];
#pragma unroll 8
      for (int k = 0; k < 32; ++k) s3 = fmaf(c2s[node * 33 + k], W3s[k * 2 + j], s3);
      int gr = r0 + node;
      if (gr < NN) logits[(size_t)gr * 2 + j] = s3;
    }
  } else {
    write_out_bf<NT, BIAS, RELU>(acc, bias, r0, lane, wv, (unsigned short*)Cout);
  }
}

// ============================ dual-B MFMA GEMM (skip + conv1) ============================
// A (hr, bf16) staged once; B1 = skipW -> hsk (+bias), then B2 = c1W -> hb + scores(H=4).
__global__ __launch_bounds__(256) void k_mgemm_dual(
    const unsigned short* __restrict__ A, const unsigned short* __restrict__ Bw1,
    const float* __restrict__ bias1, const unsigned short* __restrict__ Bw2,
    const float* __restrict__ a_s, const float* __restrict__ a_d,
    unsigned short* __restrict__ Out1, unsigned short* __restrict__ Out2,
    float* __restrict__ scs, float* __restrict__ scd) {
  constexpr int KB = 4;  // K=128
  __shared__ __align__(16) unsigned short sm[16 * KB * 512];
  const int tid = threadIdx.x;
  const int r0 = blockIdx.x * 128;
  // stage A
#pragma unroll
  for (int it = 0; it < 8; ++it) {
    int idx = it * 256 + tid;
    int r = idx >> 4;
    int k = (idx & 15) * 8;
    int gr = r0 + r;
    uint4 v = make_uint4(0, 0, 0, 0);
    if (gr < NN) v = *(const uint4*)(A + (size_t)gr * 128 + k);
    *(uint4*)&sm[((r >> 4) * KB + (k >> 5)) * 512 + (r & 15) * 32 + (k & 31)] = v;
  }
  // stage B1
#pragma unroll
  for (int it = 0; it < 8; ++it) {
    int idx = it * 256 + tid;
    *(uint4*)&sm[8 * KB * 512 + idx * 8] = *(const uint4*)(Bw1 + idx * 8);
  }
  __syncthreads();
  const int lane = tid & 63, wv = tid >> 6;
  const int lr = lane & 15, lg = lane >> 4;
  const int fidx = lr * 32 + lg * 8;
  f32x4 acc[2][8];
#pragma unroll
  for (int f = 0; f < 2; ++f)
#pragma unroll
    for (int ct = 0; ct < 8; ++ct) acc[f][ct] = (f32x4){0.f, 0.f, 0.f, 0.f};
#pragma unroll
  for (int kb = 0; kb < KB; ++kb) {
    short8 a0 = *(const short8*)&sm[((wv * 2 + 0) * KB + kb) * 512 + fidx];
    short8 a1 = *(const short8*)&sm[((wv * 2 + 1) * KB + kb) * 512 + fidx];
#pragma unroll
    for (int ct = 0; ct < 8; ++ct) {
      short8 b = *(const short8*)&sm[((8 + ct) * KB + kb) * 512 + fidx];
      acc[0][ct] = __builtin_amdgcn_mfma_f32_16x16x32_bf16(a0, b, acc[0][ct], 0, 0, 0);
      acc[1][ct] = __builtin_amdgcn_mfma_f32_16x16x32_bf16(a1, b, acc[1][ct], 0, 0, 0);
    }
  }
  write_out_bf<8, 1, 0>(acc, bias1, r0, lane, wv, Out1);
  __syncthreads();  // B region reads done
  // stage B2
#pragma unroll
  for (int it = 0; it < 8; ++it) {
    int idx = it * 256 + tid;
    *(uint4*)&sm[8 * KB * 512 + idx * 8] = *(const uint4*)(Bw2 + idx * 8);
  }
  __syncthreads();
#pragma unroll
  for (int f = 0; f < 2; ++f)
#pragma unroll
    for (int ct = 0; ct < 8; ++ct) acc[f][ct] = (f32x4){0.f, 0.f, 0.f, 0.f};
#pragma unroll
  for (int kb = 0; kb < KB; ++kb) {
    short8 a0 = *(const short8*)&sm[((wv * 2 + 0) * KB + kb) * 512 + fidx];
    short8 a1 = *(const short8*)&sm[((wv * 2 + 1) * KB + kb) * 512 + fidx];
#pragma unroll
    for (int ct = 0; ct < 8; ++ct) {
      short8 b = *(const short8*)&sm[((8 + ct) * KB + kb) * 512 + fidx];
      acc[0][ct] = __builtin_amdgcn_mfma_f32_16x16x32_bf16(a0, b, acc[0][ct], 0, 0, 0);
      acc[1][ct] = __builtin_amdgcn_mfma_f32_16x16x32_bf16(a1, b, acc[1][ct], 0, 0, 0);
    }
  }
  write_scores<8, 4>(acc, a_s, a_d, r0, lane, wv, scs, scd);
  write_out_bf<8, 0, 0>(acc, nullptr, r0, lane, wv, Out2);
}

// ============================ GAT aggregation (+ fused BN stats) ============================
// One wave per dst node; 8 groups x 2-edge unroll = 16 edges in flight;
// lane = 8 ch-lanes x 16 bf16 channels. Wave's 128 output floats -> LDS -> 64-way
// partial stats buffers (atomicAdd, block -> part[blockIdx&63]).
template <int H>
__global__ __launch_bounds__(256) void k_agg(const unsigned short* __restrict__ hp,
                                             const float* __restrict__ scs,
                                             const float* __restrict__ scd,
                                             const int* __restrict__ rowp,
                                             const int* __restrict__ srcl,
                                             const float* __restrict__ bias,
                                             unsigned short* __restrict__ out,
                                             float* __restrict__ part) {
  __shared__ float ssum[4][128], ssq[4][128];
  int tid = threadIdx.x;
  int lane = tid & 63, wv = tid >> 6;
  int n = (blockIdx.x * 256 + tid) >> 6;  // grid exact: n < NN always
  int g = lane >> 3;
  int l8 = lane & 7;
  int c0 = l8 * 16;
  int hid = (H == 1) ? 0 : (l8 >> 1);
  float sd = scd[(size_t)n * H + hid];
  int beg = rowp[n], end = rowp[n + 1];
  float a[16];
#pragma unroll
  for (int i = 0; i < 16; ++i) a[i] = 0.f;
  float sw = 0.f;
  int k = beg + g;
  for (; k + 8 < end; k += 16) {
    int s0 = srcl[k];
    int s1 = srcl[k + 8];
    float e0 = scs[(size_t)s0 * H + hid] + sd;
    float e1 = scs[(size_t)s1 * H + hid] + sd;
    const uint4* p0 = (const uint4*)(hp + (size_t)s0 * 128 + c0);
    const uint4* p1 = (const uint4*)(hp + (size_t)s1 * 128 + c0);
    uint4 u0 = p0[0], u1 = p0[1];
    uint4 v0 = p1[0], v1 = p1[1];
    e0 = fmaxf(e0, 0.f) + 0.2f * fminf(e0, 0.f);
    e1 = fmaxf(e1, 0.f) + 0.2f * fminf(e1, 0.f);
    float w0 = __expf(e0), w1 = __expf(e1);
    a[0] = fmaf(w0, bf2f_lo(u0.x), a[0]); a[1] = fmaf(w0, bf2f_hi(u0.x), a[1]);
    a[2] = fmaf(w0, bf2f_lo(u0.y), a[2]); a[3] = fmaf(w0, bf2f_hi(u0.y), a[3]);
    a[4] = fmaf(w0, bf2f_lo(u0.z), a[4]); a[5] = fmaf(w0, bf2f_hi(u0.z), a[5]);
    a[6] = fmaf(w0, bf2f_lo(u0.w), a[6]); a[7] = fmaf(w0, bf2f_hi(u0.w), a[7]);
    a[8] = fmaf(w0, bf2f_lo(u1.x), a[8]); a[9] = fmaf(w0, bf2f_hi(u1.x), a[9]);
    a[10] = fmaf(w0, bf2f_lo(u1.y), a[10]); a[11] = fmaf(w0, bf2f_hi(u1.y), a[11]);
    a[12] = fmaf(w0, bf2f_lo(u1.z), a[12]); a[13] = fmaf(w0, bf2f_hi(u1.z), a[13]);
    a[14] = fmaf(w0, bf2f_lo(u1.w), a[14]); a[15] = fmaf(w0, bf2f_hi(u1.w), a[15]);
    a[0] = fmaf(w1, bf2f_lo(v0.x), a[0]); a[1] = fmaf(w1, bf2f_hi(v0.x), a[1]);
    a[2] = fmaf(w1, bf2f_lo(v0.y), a[2]); a[3] = fmaf(w1, bf2f_hi(v0.y), a[3]);
    a[4] = fmaf(w1, bf2f_lo(v0.z), a[4]); a[5] = fmaf(w1, bf2f_hi(v0.z), a[5]);
    a[6] = fmaf(w1, bf2f_lo(v0.w), a[6]); a[7] = fmaf(w1, bf2f_hi(v0.w), a[7]);
    a[8] = fmaf(w1, bf2f_lo(v1.x), a[8]); a[9] = fmaf(w1, bf2f_hi(v1.x), a[9]);
    a[10] = fmaf(w1, bf2f_lo(v1.y), a[10]); a[11] = fmaf(w1, bf2f_hi(v1.y), a[11]);
    a[12] = fmaf(w1, bf2f_lo(v1.z), a[12]); a[13] = fmaf(w1, bf2f_hi(v1.z), a[13]);
    a[14] = fmaf(w1, bf2f_lo(v1.w), a[14]); a[15] = fmaf(w1, bf2f_hi(v1.w), a[15]);
    sw += w0 + w1;
  }
  if (k < end) {
    int s0 = srcl[k];
    float e0 = scs[(size_t)s0 * H + hid] + sd;
    const uint4* p0 = (const uint4*)(hp + (size_t)s0 * 128 + c0);
    uint4 u0 = p0[0], u1 = p0[1];
    e0 = fmaxf(e0, 0.f) + 0.2f * fminf(e0, 0.f);
    float w0 = __expf(e0);
    a[0] = fmaf(w0, bf2f_lo(u0.x), a[0]); a[1] = fmaf(w0, bf2f_hi(u0.x), a[1]);
    a[2] = fmaf(w0, bf2f_lo(u0.y), a[2]); a[3] = fmaf(w0, bf2f_hi(u0.y), a[3]);
    a[4] = fmaf(w0, bf2f_lo(u0.z), a[4]); a[5] = fmaf(w0, bf2f_hi(u0.z), a[5]);
    a[6] = fmaf(w0, bf2f_lo(u0.w), a[6]); a[7] = fmaf(w0, bf2f_hi(u0.w), a[7]);
    a[8] = fmaf(w0, bf2f_lo(u1.x), a[8]); a[9] = fmaf(w0, bf2f_hi(u1.x), a[9]);
    a[10] = fmaf(w0, bf2f_lo(u1.y), a[10]); a[11] = fmaf(w0, bf2f_hi(u1.y), a[11]);
    a[12] = fmaf(w0, bf2f_lo(u1.z), a[12]); a[13] = fmaf(w0, bf2f_hi(u1.z), a[13]);
    a[14] = fmaf(w0, bf2f_lo(u1.w), a[14]); a[15] = fmaf(w0, bf2f_hi(u1.w), a[15]);
    sw += w0;
  }
#pragma unroll
  for (int i = 0; i < 16; ++i) {
    a[i] += __shfl_xor(a[i], 8);
    a[i] += __shfl_xor(a[i], 16);
    a[i] += __shfl_xor(a[i], 32);
  }
  sw += __shfl_xor(sw, 8);
  sw += __shfl_xor(sw, 16);
  sw += __shfl_xor(sw, 32);
  if (g == 0) {
    float inv = 1.f / (sw + 1e-16f);
    unsigned wb[8];
#pragma unroll
    for (int j = 0; j < 8; ++j) {
      float o0 = a[2 * j] * inv + bias[c0 + 2 * j];
      float o1 = a[2 * j + 1] * inv + bias[c0 + 2 * j + 1];
      ssum[wv][c0 + 2 * j] = o0;
      ssum[wv][c0 + 2 * j + 1] = o1;
      ssq[wv][c0 + 2 * j] = o0 * o0;
      ssq[wv][c0 + 2 * j + 1] = o1 * o1;
      wb[j] = (unsigned)f2bf(o0) | ((unsigned)f2bf(o1) << 16);
    }
    *(uint4*)(out + (size_t)n * 128 + c0) = make_uint4(wb[0], wb[1], wb[2], wb[3]);
    *(uint4*)(out + (size_t)n * 128 + c0 + 8) = make_uint4(wb[4], wb[5], wb[6], wb[7]);
  }
  __syncthreads();
  if (tid < 128) {
    float s = ssum[0][tid] + ssum[1][tid] + ssum[2][tid] + ssum[3][tid];
    float q = ssq[0][tid] + ssq[1][tid] + ssq[2][tid] + ssq[3][tid];
    int pb = (blockIdx.x & 63) * 256;
    atomicAdd(&part[pb + tid], s);
    atomicAdd(&part[pb + 128 + tid], q);
  }
}

// ============================ launch ============================
extern "C" void kernel_launch(void* const* d_in, const int* in_sizes, int n_in,
                              void* d_out, int out_size, void* d_ws, size_t ws_size,
                              hipStream_t stream) {
  (void)in_sizes; (void)n_in; (void)out_size; (void)ws_size;
  const float* x       = (const float*)d_in[0];
  const int*   ei      = (const int*)d_in[1];
  const float* in_g    = (const float*)d_in[2];
  const float* in_b    = (const float*)d_in[3];
  const float* projW   = (const float*)d_in[4];
  const float* projb   = (const float*)d_in[5];
  const float* skipW   = (const float*)d_in[6];
  const float* skipb   = (const float*)d_in[7];
  const float* c1W     = (const float*)d_in[8];
  const float* c1as    = (const float*)d_in[9];
  const float* c1ad    = (const float*)d_in[10];
  const float* c1b     = (const float*)d_in[11];
  const float* bn1g    = (const float*)d_in[12];
  const float* bn1b    = (const float*)d_in[13];
  const float* c2W     = (const float*)d_in[14];
  const float* c2as    = (const float*)d_in[15];
  const float* c2ad    = (const float*)d_in[16];
  const float* c2b     = (const float*)d_in[17];
  const float* bn2g    = (const float*)d_in[18];
  const float* bn2b    = (const float*)d_in[19];
  const float* c3W     = (const float*)d_in[20];
  const float* c3as    = (const float*)d_in[21];
  const float* c3ad    = (const float*)d_in[22];
  const float* c3b     = (const float*)d_in[23];
  const float* bn3g    = (const float*)d_in[24];
  const float* bn3b    = (const float*)d_in[25];
  const float* clsW1   = (const float*)d_in[26];
  const float* clsb1   = (const float*)d_in[27];
  const float* clsW2   = (const float*)d_in[28];
  const float* clsb2   = (const float*)d_in[29];
  const float* clsW3   = (const float*)d_in[30];
  const float* clsb3   = (const float*)d_in[31];
  const float* confW   = (const float*)d_in[32];
  const float* confb   = (const float*)d_in[33];

  float* out_logits = (float*)d_out;
  float* out_conf   = (float*)d_out + (size_t)NN * 2;

  char* p = (char*)d_ws;
  auto alloc = [&](size_t bytes) -> char* {
    char* r = p;
    p += (bytes + 255) & ~(size_t)255;
    return r;
  };
  unsigned short* hr  = (unsigned short*)alloc((size_t)NN * 128 * 2);  // relu(proj)
  unsigned short* hsk = (unsigned short*)alloc((size_t)NN * 128 * 2);  // h_skip
  unsigned short* hb  = (unsigned short*)alloc((size_t)NN * 128 * 2);  // conv h
  unsigned short* agA = (unsigned short*)alloc((size_t)NN * 128 * 2);  // agg out (L1, L3)
  unsigned short* agB = (unsigned short*)alloc((size_t)NN * 128 * 2);  // agg out (L2)
  float* scs   = (float*)alloc((size_t)NN * 4 * 4);
  float* scd   = (float*)alloc((size_t)NN * 4 * 4);
  // zero region: gpos | stats(x) | part1 | part2 | part3
  char*  zr    = alloc(2048 + 1024 + 3 * 65536);
  int*   gpos  = (int*)zr;
  float* stats = (float*)(zr + 2048);
  float* part1 = stats + 256;
  float* part2 = part1 + 16384;
  float* part3 = part2 + 16384;
  int*   rowp  = (int*)alloc((size_t)(NN + 1) * 4);
  int*   ebase = (int*)alloc((size_t)NBK * 4);
  unsigned* binned = (unsigned*)alloc((size_t)NBK * BCAP * 4);
  int*   srcl  = (int*)alloc((size_t)TOT_E * 4);
  unsigned short* wr = (unsigned short*)alloc(83968 * 2);
  unsigned short* wr_proj = wr;
  unsigned short* wr_skip = wr + 8192;
  unsigned short* wr_c1   = wr + 24576;
  unsigned short* wr_c2   = wr + 40960;
  unsigned short* wr_c3   = wr + 57344;
  unsigned short* wr_cls  = wr + 73728;

  const int GB = (NN + 127) / 128;  // 391
  const int WB = (NN + 3) / 4;      // 12500 (exact: 12500*4 == NN)

  k_reorder_all<<<328, 256, 0, stream>>>(projW, skipW, c1W, c2W, c3W, clsW1, confW, wr);
  hipMemsetAsync(zr, 0, 2048 + 1024 + 3 * 65536, stream);

  // ---- CSR build ----
  k_bin<<<256, 512, 0, stream>>>(ei, gpos, binned);
  k_bscan<<<1, 512, 0, stream>>>(gpos, ebase, rowp);
  k_bucket<<<NBK, 256, 0, stream>>>(binned, gpos, ebase, rowp, srcl);

  // ---- input BN stats ----
  k_bn_stats64<<<256, 256, 0, stream>>>(x, stats);

  // ---- proj: hr = relu(bn(x) @ projW + b) ----
  k_mgemm<64, 8, 0, 1, 0, 1, 1, 1, 0><<<GB, 256, 0, stream>>>(
      x, wr_proj, projb, stats, in_g, in_b, nullptr, nullptr, nullptr, nullptr,
      hr, nullptr, nullptr, nullptr, nullptr, nullptr, nullptr, nullptr, nullptr);

  // ---- dual: hsk = hr@skipW+b ; h1 = hr@c1W (+scores) ----
  k_mgemm_dual<<<GB, 256, 0, stream>>>(hr, wr_skip, skipb, wr_c1, c1as, c1ad,
                                       hsk, hb, scs, scd);
  k_agg<4><<<WB, 256, 0, stream>>>(hb, scs, scd, rowp, srcl, c1b, agA, part1);

  // ---- GAT layer 2 (bn1+relu fused into A staging) ----
  k_mgemm<128, 8, 1, 2, 1, 0, 0, 1, 4><<<GB, 256, 0, stream>>>(
      agA, wr_c2, nullptr, part1, bn1g, bn1b, nullptr, c2as, c2ad, nullptr,
      hb, nullptr, scs, scd, nullptr, nullptr, nullptr, nullptr, nullptr);
  k_agg<4><<<WB, 256, 0, stream>>>(hb, scs, scd, rowp, srcl, c2b, agB, part2);

  // ---- GAT layer 3 (H=1; bn2+relu fused) ----
  k_mgemm<128, 8, 1, 2, 1, 0, 0, 1, 1><<<GB, 256, 0, stream>>>(
      agB, wr_c3, nullptr, part2, bn2g, bn2b, nullptr, c3as, c3ad, nullptr,
      hb, nullptr, scs, scd, nullptr, nullptr, nullptr, nullptr, nullptr);
  k_agg<1><<<WB, 256, 0, stream>>>(hb, scs, scd, rowp, srcl, c3b, agA, part3);

  // ---- classifier: relu(bn3(agA)+hsk) @ [W1|confW] -> C1(LDS) -> c2 -> logits/conf ----
  k_mgemm<128, 5, 1, 3, 1, 1, 0, 2, 0><<<GB, 256, 0, stream>>>(
      agA, wr_cls, clsb1, part3, bn3g, bn3b, hsk, nullptr, nullptr, confb,
      nullptr, out_conf, nullptr, nullptr, clsW2, clsb2, clsW3, clsb3, out_logits);
}